// Round 16
// baseline (831.334 us; speedup 1.0000x reference)
//
#include <hip/hip_runtime.h>
#include <hip/hip_bf16.h>
#include <stdint.h>

#define S_LEN  2048
#define DMODEL 2048
#define NBATCH 2
#define NHEADS 16
#define DHEAD  128
#define HID    8192
#define NROWS  4096   // NBATCH * S_LEN

typedef unsigned short u16;
typedef unsigned int   u32;
typedef __attribute__((ext_vector_type(8))) short s16x8;   // 8 bf16 = MFMA A/B frag
typedef __attribute__((ext_vector_type(4))) float f32x4;   // MFMA C/D frag

static __device__ __forceinline__ float bf2f(u16 b) {
  return __uint_as_float(((u32)b) << 16);
}
static __device__ __forceinline__ u16 f2bf(float f) {
  u32 u = __float_as_uint(f);
  return (u16)((u + 0x7fffu + ((u >> 16) & 1u)) >> 16);   // RNE
}

// async global->LDS, 16B per lane
static __device__ __forceinline__ void gload16(const void* gp, void* lp) {
  __builtin_amdgcn_global_load_lds(
      (const __attribute__((address_space(1))) void*)gp,
      (__attribute__((address_space(3))) void*)lp, 16, 0, 0);
}

// 16-lane (DPP row) rotate-butterfly reductions — VALU pipe, no LDS traffic
#define DPP_ROR(v, C) \
  __int_as_float(__builtin_amdgcn_update_dpp(0, __float_as_int(v), C, 0xf, 0xf, true))
static __device__ __forceinline__ float red16_max(float v) {
  v = fmaxf(v, DPP_ROR(v, 0x121));
  v = fmaxf(v, DPP_ROR(v, 0x122));
  v = fmaxf(v, DPP_ROR(v, 0x124));
  v = fmaxf(v, DPP_ROR(v, 0x128));
  return v;
}
static __device__ __forceinline__ float red16_sum(float v) {
  v += DPP_ROR(v, 0x121);
  v += DPP_ROR(v, 0x122);
  v += DPP_ROR(v, 0x124);
  v += DPP_ROR(v, 0x128);
  return v;
}

// ---------------------------------------------------------------------------
// Weight prep: W[K][N] f32 -> Wt[N][K] bf16. Write-vectorized (ushort4/thread).
// ---------------------------------------------------------------------------
__global__ __launch_bounds__(256) void transpose_cvt(const float* __restrict__ W,
                                                     u16* __restrict__ Wt,
                                                     int K, int N) {
  __shared__ float tile[32][33];
  const int tx = threadIdx.x, ty = threadIdx.y;       // 32 x 8
  const int n0 = blockIdx.x * 32, k0 = blockIdx.y * 32;
#pragma unroll
  for (int i = 0; i < 4; ++i)
    tile[ty + i * 8][tx] = W[(size_t)(k0 + ty + i * 8) * N + n0 + tx];
  __syncthreads();
  const int t = ty * 32 + tx;
  const int n = t >> 3, k4 = (t & 7) * 4;             // 8 threads span one n-row
  ushort4 o;
  o.x = f2bf(tile[k4 + 0][n]);
  o.y = f2bf(tile[k4 + 1][n]);
  o.z = f2bf(tile[k4 + 2][n]);
  o.w = f2bf(tile[k4 + 3][n]);
  *(ushort4*)&Wt[(size_t)(n0 + n) * K + k0 + k4] = o;
}

// ---------------------------------------------------------------------------
// RMSNorm: row of f32 [DMODEL] -> bf16, one block per row
// ---------------------------------------------------------------------------
__global__ __launch_bounds__(256) void rmsnorm_k(const float* __restrict__ x,
                                                 const float* __restrict__ g,
                                                 u16* __restrict__ out) {
  const int row = blockIdx.x;
  const int tid = threadIdx.x;
  const float4* xr = (const float4*)(x + (size_t)row * DMODEL);
  float4 v0 = xr[tid];
  float4 v1 = xr[tid + 256];
  float ss = v0.x * v0.x + v0.y * v0.y + v0.z * v0.z + v0.w * v0.w +
             v1.x * v1.x + v1.y * v1.y + v1.z * v1.z + v1.w * v1.w;
#pragma unroll
  for (int o = 1; o < 64; o <<= 1) ss += __shfl_xor(ss, o);
  __shared__ float red[4];
  if ((tid & 63) == 0) red[tid >> 6] = ss;
  __syncthreads();
  const float tot = red[0] + red[1] + red[2] + red[3];
  const float rms = rsqrtf(tot * (1.0f / DMODEL) + 1e-6f);
  const float4* gr = (const float4*)g;
  float4 g0 = gr[tid], g1 = gr[tid + 256];
  ushort4 o0, o1;
  o0.x = f2bf(v0.x * rms * g0.x); o0.y = f2bf(v0.y * rms * g0.y);
  o0.z = f2bf(v0.z * rms * g0.z); o0.w = f2bf(v0.w * rms * g0.w);
  o1.x = f2bf(v1.x * rms * g1.x); o1.y = f2bf(v1.y * rms * g1.y);
  o1.z = f2bf(v1.z * rms * g1.z); o1.w = f2bf(v1.w * rms * g1.w);
  ushort4* orow = (ushort4*)(out + (size_t)row * DMODEL);
  orow[tid] = o0;
  orow[tid + 256] = o1;
}

// ---------------------------------------------------------------------------
// Pipelined fused SwiGLU GEMM — ONE barrier per K-tile (r15-proven).
// ---------------------------------------------------------------------------
__global__ __launch_bounds__(512, 1) void gemm8_swiglu(const u16* __restrict__ A,
                                                       const u16* __restrict__ B1t,
                                                       const u16* __restrict__ B3t,
                                                       u16* __restrict__ U) {
  __shared__ __align__(16) u16 As2[2][16384];   // 2 x 32 KB ([256 r][64 k])
  __shared__ __align__(16) u16 Bs2[2][16384];   // 2 x 32 KB ([256 br][64 k])
  const int tid = threadIdx.x;
  const int lane = tid & 63, wave = tid >> 6;
  const int g = lane >> 4, cl = lane & 15;
  const int wr = wave >> 2, wc = wave & 3;      // 2M x 4N
  const int bx = blockIdx.x;                    // U cols [bx*128, +128)
  const int m0 = blockIdx.y << 8;               // A rows [m0, m0+256)
  const int K2 = DMODEL * 2;                    // row stride in bytes

  const char* pA[4];
  const char* pB[4];
#pragma unroll
  for (int i = 0; i < 4; ++i) {
    const int o = i * 8192 + tid * 16;          // byte offset in 32KB tile
    const int op = o ^ (((o >> 7) & 7) << 4);
    const int row = op >> 7, colb = op & 127;
    pA[i] = (const char*)A + (size_t)(m0 + row) * K2 + colb;
    const int pl = row >> 5, half = (row >> 4) & 1, c = row & 15;
    const int grow = bx * 128 + pl * 16 + c;
    pB[i] = (const char*)(half ? B3t : B1t) + (size_t)grow * K2 + colb;
  }

  int aoff[8], boff[4];
#pragma unroll
  for (int m = 0; m < 8; ++m)
    aoff[m] = (wr * 128 + m * 16 + cl) * 128 + ((g * 16) ^ ((cl & 7) << 4));
#pragma unroll
  for (int n = 0; n < 4; ++n)
    boff[n] = (wc * 64 + n * 16 + cl) * 128 + ((g * 16) ^ ((cl & 7) << 4));

  const f32x4 fz = {0.f, 0.f, 0.f, 0.f};
  f32x4 acc[8][4];
#pragma unroll
  for (int i = 0; i < 8; ++i)
#pragma unroll
    for (int j = 0; j < 4; ++j) acc[i][j] = fz;

  const int NT = DMODEL / 64;   // 32 K-tiles

  {
    u16* da = &As2[0][wave * 512];
    u16* db = &Bs2[0][wave * 512];
#pragma unroll
    for (int i = 0; i < 4; ++i) gload16(pA[i], da + i * 4096);
#pragma unroll
    for (int i = 0; i < 4; ++i) gload16(pB[i], db + i * 4096);
  }
  asm volatile("s_waitcnt vmcnt(0)" ::: "memory");
  __builtin_amdgcn_s_barrier();

  int s = 0;
#pragma unroll 1
  for (int t = 0; t < NT; ++t) {
    const char* as = (const char*)&As2[s][0];
    const char* bs = (const char*)&Bs2[s][0];
    const bool pf = (t + 1 < NT);
    const size_t ko = (size_t)(t + 1) * 128;
    u16* da = &As2[s ^ 1][wave * 512];
    u16* db = &Bs2[s ^ 1][wave * 512];

    s16x8 afr[4][2], bf0[2][2], bf1[2][2];
    // ph0 (m0,n0)
#pragma unroll
    for (int i = 0; i < 4; ++i) {
      afr[i][0] = *(const s16x8*)(as + aoff[i]);
      afr[i][1] = *(const s16x8*)(as + (aoff[i] ^ 64));
    }
#pragma unroll
    for (int j = 0; j < 2; ++j) {
      bf0[j][0] = *(const s16x8*)(bs + boff[j]);
      bf0[j][1] = *(const s16x8*)(bs + (boff[j] ^ 64));
    }
    if (pf) {
#pragma unroll
      for (int i = 0; i < 4; ++i) gload16(pA[i] + ko, da + i * 4096);
    }
    asm volatile("s_waitcnt lgkmcnt(0)" ::: "memory");
    __builtin_amdgcn_sched_barrier(0);
    __builtin_amdgcn_s_setprio(1);
#pragma unroll
    for (int i = 0; i < 4; ++i)
#pragma unroll
      for (int j = 0; j < 2; ++j)
#pragma unroll
        for (int kk = 0; kk < 2; ++kk)
          acc[i][j] = __builtin_amdgcn_mfma_f32_16x16x32_bf16(
              afr[i][kk], bf0[j][kk], acc[i][j], 0, 0, 0);
    __builtin_amdgcn_s_setprio(0);
    // ph1 (m0,n1)
#pragma unroll
    for (int j = 0; j < 2; ++j) {
      bf1[j][0] = *(const s16x8*)(bs + boff[2 + j]);
      bf1[j][1] = *(const s16x8*)(bs + (boff[2 + j] ^ 64));
    }
    if (pf) {
#pragma unroll
      for (int i = 0; i < 4; ++i) gload16(pB[i] + ko, db + i * 4096);
    }
    asm volatile("s_waitcnt lgkmcnt(0)" ::: "memory");
    __builtin_amdgcn_sched_barrier(0);
    __builtin_amdgcn_s_setprio(1);
#pragma unroll
    for (int i = 0; i < 4; ++i)
#pragma unroll
      for (int j = 0; j < 2; ++j)
#pragma unroll
        for (int kk = 0; kk < 2; ++kk)
          acc[i][2 + j] = __builtin_amdgcn_mfma_f32_16x16x32_bf16(
              afr[i][kk], bf1[j][kk], acc[i][2 + j], 0, 0, 0);
    __builtin_amdgcn_s_setprio(0);
    // ph2 (m1,n1)
#pragma unroll
    for (int i = 0; i < 4; ++i) {
      afr[i][0] = *(const s16x8*)(as + aoff[4 + i]);
      afr[i][1] = *(const s16x8*)(as + (aoff[4 + i] ^ 64));
    }
    asm volatile("s_waitcnt lgkmcnt(0)" ::: "memory");
    __builtin_amdgcn_sched_barrier(0);
    __builtin_amdgcn_s_setprio(1);
#pragma unroll
    for (int i = 0; i < 4; ++i)
#pragma unroll
      for (int j = 0; j < 2; ++j)
#pragma unroll
        for (int kk = 0; kk < 2; ++kk)
          acc[4 + i][2 + j] = __builtin_amdgcn_mfma_f32_16x16x32_bf16(
              afr[i][kk], bf1[j][kk], acc[4 + i][2 + j], 0, 0, 0);
    __builtin_amdgcn_s_setprio(0);
    // ph3 (m1,n0) — pure MFMA
    __builtin_amdgcn_s_setprio(1);
#pragma unroll
    for (int i = 0; i < 4; ++i)
#pragma unroll
      for (int j = 0; j < 2; ++j)
#pragma unroll
        for (int kk = 0; kk < 2; ++kk)
          acc[4 + i][j] = __builtin_amdgcn_mfma_f32_16x16x32_bf16(
              afr[i][kk], bf0[j][kk], acc[4 + i][j], 0, 0, 0);
    __builtin_amdgcn_s_setprio(0);
    if (pf) asm volatile("s_waitcnt vmcnt(0)" ::: "memory");
    __builtin_amdgcn_s_barrier();
    s ^= 1;
  }

  const int orow0 = m0 + wr * 128 + g * 4;
#pragma unroll
  for (int m = 0; m < 8; ++m)
#pragma unroll
    for (int p = 0; p < 2; ++p) {
      const int col = bx * 128 + wc * 32 + p * 16 + cl;
      const f32x4 a1 = acc[m][p * 2];
      const f32x4 a3 = acc[m][p * 2 + 1];
#pragma unroll
      for (int r = 0; r < 4; ++r) {
        const float a = a1[r];
        const float v = (a / (1.f + __expf(-a))) * a3[r];
        U[(size_t)(orow0 + m * 16 + r) * HID + col] = f2bf(v);
      }
    }
}

// ---------------------------------------------------------------------------
// Pipelined down-projection GEMM, split-K=2 — one barrier per K-tile.
// ---------------------------------------------------------------------------
__global__ __launch_bounds__(512, 1) void gemm8_down(const u16* __restrict__ A,
                                                     const u16* __restrict__ Bt,
                                                     float* __restrict__ P) {
  __shared__ __align__(16) u16 As2[2][16384];
  __shared__ __align__(16) u16 Bs2[2][16384];
  const int tid = threadIdx.x;
  const int lane = tid & 63, wave = tid >> 6;
  const int g = lane >> 4, cl = lane & 15;
  const int wr = wave >> 2, wc = wave & 3;
  const int bx = blockIdx.x;
  const int m0 = blockIdx.y << 8;
  const int kz = blockIdx.z;
  const int K2 = HID * 2;
  const size_t kzoff = (size_t)kz * 4096 * 2;

  const char* pA[4];
  const char* pB[4];
#pragma unroll
  for (int i = 0; i < 4; ++i) {
    const int o = i * 8192 + tid * 16;
    const int op = o ^ (((o >> 7) & 7) << 4);
    const int row = op >> 7, colb = op & 127;
    pA[i] = (const char*)A + (size_t)(m0 + row) * K2 + colb + kzoff;
    pB[i] = (const char*)Bt + (size_t)(bx * 256 + row) * K2 + colb + kzoff;
  }

  int aoff[8], boff[4];
#pragma unroll
  for (int m = 0; m < 8; ++m)
    aoff[m] = (wr * 128 + m * 16 + cl) * 128 + ((g * 16) ^ ((cl & 7) << 4));
#pragma unroll
  for (int n = 0; n < 4; ++n)
    boff[n] = (wc * 64 + n * 16 + cl) * 128 + ((g * 16) ^ ((cl & 7) << 4));

  const f32x4 fz = {0.f, 0.f, 0.f, 0.f};
  f32x4 acc[8][4];
#pragma unroll
  for (int i = 0; i < 8; ++i)
#pragma unroll
    for (int j = 0; j < 4; ++j) acc[i][j] = fz;

  const int NT = 4096 / 64;

  {
    u16* da = &As2[0][wave * 512];
    u16* db = &Bs2[0][wave * 512];
#pragma unroll
    for (int i = 0; i < 4; ++i) gload16(pA[i], da + i * 4096);
#pragma unroll
    for (int i = 0; i < 4; ++i) gload16(pB[i], db + i * 4096);
  }
  asm volatile("s_waitcnt vmcnt(0)" ::: "memory");
  __builtin_amdgcn_s_barrier();

  int s = 0;
#pragma unroll 1
  for (int t = 0; t < NT; ++t) {
    const char* as = (const char*)&As2[s][0];
    const char* bs = (const char*)&Bs2[s][0];
    const bool pf = (t + 1 < NT);
    const size_t ko = (size_t)(t + 1) * 128;
    u16* da = &As2[s ^ 1][wave * 512];
    u16* db = &Bs2[s ^ 1][wave * 512];

    s16x8 afr[4][2], bf0[2][2], bf1[2][2];
    // ph0
#pragma unroll
    for (int i = 0; i < 4; ++i) {
      afr[i][0] = *(const s16x8*)(as + aoff[i]);
      afr[i][1] = *(const s16x8*)(as + (aoff[i] ^ 64));
    }
#pragma unroll
    for (int j = 0; j < 2; ++j) {
      bf0[j][0] = *(const s16x8*)(bs + boff[j]);
      bf0[j][1] = *(const s16x8*)(bs + (boff[j] ^ 64));
    }
    if (pf) {
#pragma unroll
      for (int i = 0; i < 4; ++i) gload16(pA[i] + ko, da + i * 4096);
    }
    asm volatile("s_waitcnt lgkmcnt(0)" ::: "memory");
    __builtin_amdgcn_sched_barrier(0);
    __builtin_amdgcn_s_setprio(1);
#pragma unroll
    for (int i = 0; i < 4; ++i)
#pragma unroll
      for (int j = 0; j < 2; ++j)
#pragma unroll
        for (int kk = 0; kk < 2; ++kk)
          acc[i][j] = __builtin_amdgcn_mfma_f32_16x16x32_bf16(
              afr[i][kk], bf0[j][kk], acc[i][j], 0, 0, 0);
    __builtin_amdgcn_s_setprio(0);
    // ph1
#pragma unroll
    for (int j = 0; j < 2; ++j) {
      bf1[j][0] = *(const s16x8*)(bs + boff[2 + j]);
      bf1[j][1] = *(const s16x8*)(bs + (boff[2 + j] ^ 64));
    }
    if (pf) {
#pragma unroll
      for (int i = 0; i < 4; ++i) gload16(pB[i] + ko, db + i * 4096);
    }
    asm volatile("s_waitcnt lgkmcnt(0)" ::: "memory");
    __builtin_amdgcn_sched_barrier(0);
    __builtin_amdgcn_s_setprio(1);
#pragma unroll
    for (int i = 0; i < 4; ++i)
#pragma unroll
      for (int j = 0; j < 2; ++j)
#pragma unroll
        for (int kk = 0; kk < 2; ++kk)
          acc[i][2 + j] = __builtin_amdgcn_mfma_f32_16x16x32_bf16(
              afr[i][kk], bf1[j][kk], acc[i][2 + j], 0, 0, 0);
    __builtin_amdgcn_s_setprio(0);
    // ph2
#pragma unroll
    for (int i = 0; i < 4; ++i) {
      afr[i][0] = *(const s16x8*)(as + aoff[4 + i]);
      afr[i][1] = *(const s16x8*)(as + (aoff[4 + i] ^ 64));
    }
    asm volatile("s_waitcnt lgkmcnt(0)" ::: "memory");
    __builtin_amdgcn_sched_barrier(0);
    __builtin_amdgcn_s_setprio(1);
#pragma unroll
    for (int i = 0; i < 4; ++i)
#pragma unroll
      for (int j = 0; j < 2; ++j)
#pragma unroll
        for (int kk = 0; kk < 2; ++kk)
          acc[4 + i][2 + j] = __builtin_amdgcn_mfma_f32_16x16x32_bf16(
              afr[i][kk], bf1[j][kk], acc[4 + i][2 + j], 0, 0, 0);
    __builtin_amdgcn_s_setprio(0);
    // ph3
    __builtin_amdgcn_s_setprio(1);
#pragma unroll
    for (int i = 0; i < 4; ++i)
#pragma unroll
      for (int j = 0; j < 2; ++j)
#pragma unroll
        for (int kk = 0; kk < 2; ++kk)
          acc[4 + i][j] = __builtin_amdgcn_mfma_f32_16x16x32_bf16(
              afr[i][kk], bf0[j][kk], acc[4 + i][j], 0, 0, 0);
    __builtin_amdgcn_s_setprio(0);
    if (pf) asm volatile("s_waitcnt vmcnt(0)" ::: "memory");
    __builtin_amdgcn_s_barrier();
    s ^= 1;
  }

  float* Pz = P + (size_t)kz * NROWS * DMODEL;
  const int orow0 = m0 + wr * 128 + g * 4;
#pragma unroll
  for (int m = 0; m < 8; ++m)
#pragma unroll
    for (int n = 0; n < 4; ++n) {
      const int col = bx * 256 + wc * 64 + n * 16 + cl;
#pragma unroll
      for (int r = 0; r < 4; ++r)
        Pz[(size_t)(orow0 + m * 16 + r) * DMODEL + col] = acc[m][n][r];
    }
}

// ---------------------------------------------------------------------------
// Fused QKV GEMM — BN=128, grid (16,16,3) = 768 blocks = EXACTLY 3 full
// scheduling rounds at 1 block/CU (the r12-r15 BN=256 version launched 384
// blocks = 1.5 rounds -> 75% tail utilization). Body = proven wo shape.
// z=0: Q row layout; z=1: K granule; z=2: V granule.
// ---------------------------------------------------------------------------
__global__ __launch_bounds__(512, 1) void gemm8_qkv(const u16* __restrict__ A,
                                                    const u16* __restrict__ WQ,
                                                    const u16* __restrict__ WK,
                                                    const u16* __restrict__ WV,
                                                    u16* __restrict__ QB,
                                                    u16* __restrict__ KG,
                                                    u16* __restrict__ VG) {
  __shared__ __align__(16) u16 As2[2][16384];   // 2 x 32 KB (256 rows)
  __shared__ __align__(16) u16 Bs2[2][8192];    // 2 x 16 KB (128 rows)
  const int tid = threadIdx.x;
  const int lane = tid & 63, wave = tid >> 6;
  const int g = lane >> 4, cl = lane & 15;
  const int wr = wave >> 2, wc = wave & 3;      // 2M x 4N
  const int bx = blockIdx.x;                    // out cols [bx*128, +128)
  const int m0 = blockIdx.y << 8;
  const int z = blockIdx.z;                     // 0=Q 1=K 2=V
  const int K2 = DMODEL * 2;
  const u16* Bt = (z == 0) ? WQ : (z == 1) ? WK : WV;

  const char* pA[4];
  const char* pB[2];
#pragma unroll
  for (int i = 0; i < 4; ++i) {
    const int o = i * 8192 + tid * 16;
    const int op = o ^ (((o >> 7) & 7) << 4);
    const int row = op >> 7, colb = op & 127;
    pA[i] = (const char*)A + (size_t)(m0 + row) * K2 + colb;
  }
#pragma unroll
  for (int i = 0; i < 2; ++i) {
    const int o = i * 8192 + tid * 16;
    const int op = o ^ (((o >> 7) & 7) << 4);
    const int row = op >> 7, colb = op & 127;
    pB[i] = (const char*)Bt + (size_t)(bx * 128 + row) * K2 + colb;
  }

  int aoff[8], boff[2];
#pragma unroll
  for (int m = 0; m < 8; ++m)
    aoff[m] = (wr * 128 + m * 16 + cl) * 128 + ((g * 16) ^ ((cl & 7) << 4));
#pragma unroll
  for (int n = 0; n < 2; ++n)
    boff[n] = (wc * 32 + n * 16 + cl) * 128 + ((g * 16) ^ ((cl & 7) << 4));

  const f32x4 fz = {0.f, 0.f, 0.f, 0.f};
  f32x4 acc[8][2];
#pragma unroll
  for (int i = 0; i < 8; ++i)
#pragma unroll
    for (int j = 0; j < 2; ++j) acc[i][j] = fz;

  const int NT = DMODEL / 64;   // 32 K-tiles

  {
    u16* da = &As2[0][wave * 512];
    u16* db = &Bs2[0][wave * 512];
#pragma unroll
    for (int i = 0; i < 4; ++i) gload16(pA[i], da + i * 4096);
#pragma unroll
    for (int i = 0; i < 2; ++i) gload16(pB[i], db + i * 4096);
  }
  asm volatile("s_waitcnt vmcnt(0)" ::: "memory");
  __builtin_amdgcn_s_barrier();

  int s = 0;
#pragma unroll 1
  for (int t = 0; t < NT; ++t) {
    const char* as = (const char*)&As2[s][0];
    const char* bs = (const char*)&Bs2[s][0];
    const bool pf = (t + 1 < NT);
    const size_t ko = (size_t)(t + 1) * 128;
    u16* da = &As2[s ^ 1][wave * 512];
    u16* db = &Bs2[s ^ 1][wave * 512];

    s16x8 afr[4][2], bf_[2][2];
    // ph0: m-half 0
#pragma unroll
    for (int i = 0; i < 4; ++i) {
      afr[i][0] = *(const s16x8*)(as + aoff[i]);
      afr[i][1] = *(const s16x8*)(as + (aoff[i] ^ 64));
    }
#pragma unroll
    for (int j = 0; j < 2; ++j) {
      bf_[j][0] = *(const s16x8*)(bs + boff[j]);
      bf_[j][1] = *(const s16x8*)(bs + (boff[j] ^ 64));
    }
    if (pf) {
#pragma unroll
      for (int i = 0; i < 4; ++i) gload16(pA[i] + ko, da + i * 4096);
    }
    asm volatile("s_waitcnt lgkmcnt(0)" ::: "memory");
    __builtin_amdgcn_sched_barrier(0);
    __builtin_amdgcn_s_setprio(1);
#pragma unroll
    for (int i = 0; i < 4; ++i)
#pragma unroll
      for (int j = 0; j < 2; ++j)
#pragma unroll
        for (int kk = 0; kk < 2; ++kk)
          acc[i][j] = __builtin_amdgcn_mfma_f32_16x16x32_bf16(
              afr[i][kk], bf_[j][kk], acc[i][j], 0, 0, 0);
    __builtin_amdgcn_s_setprio(0);
    // ph1: m-half 1
#pragma unroll
    for (int i = 0; i < 4; ++i) {
      afr[i][0] = *(const s16x8*)(as + aoff[4 + i]);
      afr[i][1] = *(const s16x8*)(as + (aoff[4 + i] ^ 64));
    }
    if (pf) {
#pragma unroll
      for (int i = 0; i < 2; ++i) gload16(pB[i] + ko, db + i * 4096);
    }
    asm volatile("s_waitcnt lgkmcnt(0)" ::: "memory");
    __builtin_amdgcn_sched_barrier(0);
    __builtin_amdgcn_s_setprio(1);
#pragma unroll
    for (int i = 0; i < 4; ++i)
#pragma unroll
      for (int j = 0; j < 2; ++j)
#pragma unroll
        for (int kk = 0; kk < 2; ++kk)
          acc[4 + i][j] = __builtin_amdgcn_mfma_f32_16x16x32_bf16(
              afr[i][kk], bf_[j][kk], acc[4 + i][j], 0, 0, 0);
    __builtin_amdgcn_s_setprio(0);
    if (pf) asm volatile("s_waitcnt vmcnt(0)" ::: "memory");
    __builtin_amdgcn_s_barrier();
    s ^= 1;
  }

  // ---- epilogues (C/D layout: col=lane&15, row=(lane>>4)*4+reg) ----
  const int orow0 = m0 + wr * 128 + g * 4;
  if (z == 0) {
#pragma unroll
    for (int m = 0; m < 8; ++m)
#pragma unroll
      for (int n = 0; n < 2; ++n) {
        const int col = bx * 128 + wc * 32 + n * 16 + cl;
#pragma unroll
        for (int r = 0; r < 4; ++r)
          QB[(size_t)(orow0 + m * 16 + r) * DMODEL + col] = f2bf(acc[m][n][r]);
      }
  } else if (z == 1) {
#pragma unroll
    for (int m = 0; m < 8; ++m) {
      const int row0 = orow0 + m * 16;
      const int b = row0 >> 11, s0 = row0 & 2047;
#pragma unroll
      for (int n = 0; n < 2; ++n) {
        const int col = bx * 128 + wc * 32 + n * 16 + cl;
        const int hh = col >> 7, dd = col & 127;
        u16* pg = KG + (size_t)((b * NHEADS + hh) * 32 + (s0 >> 6)) * 8192 +
                  ((dd >> 3) * 64 + (s0 & 63)) * 8 + (dd & 7);
#pragma unroll
        for (int r = 0; r < 4; ++r) pg[r * 8] = f2bf(acc[m][n][r]);
      }
    }
  } else {
#pragma unroll
    for (int m = 0; m < 8; ++m) {
      const int row0 = orow0 + m * 16;
      const int b = row0 >> 11, s0 = row0 & 2047;
#pragma unroll
      for (int n = 0; n < 2; ++n) {
        const int col = bx * 128 + wc * 32 + n * 16 + cl;
        const int hh = col >> 7, dd = col & 127;
        ushort4 o;
        o.x = f2bf(acc[m][n][0]); o.y = f2bf(acc[m][n][1]);
        o.z = f2bf(acc[m][n][2]); o.w = f2bf(acc[m][n][3]);
        *(ushort4*)(VG + (size_t)((b * NHEADS + hh) * 32 + (s0 >> 6)) * 8192 +
                    (((s0 & 63) >> 3) * 128 + dd) * 8 + (s0 & 7)) = o;
      }
    }
  }
}

// ---------------------------------------------------------------------------
// Pipelined wo projection: X1 = AO·WOt^T + x. (r15-proven, stride fix in)
// ---------------------------------------------------------------------------
__global__ __launch_bounds__(512, 1) void gemm8_wo(const u16* __restrict__ A,
                                                   const u16* __restrict__ Bt,
                                                   const float* __restrict__ resid,
                                                   float* __restrict__ X1out) {
  __shared__ __align__(16) u16 As2[2][16384];   // 2 x 32 KB (256 rows)
  __shared__ __align__(16) u16 Bs2[2][8192];    // 2 x 16 KB (128 rows)
  const int tid = threadIdx.x;
  const int lane = tid & 63, wave = tid >> 6;
  const int g = lane >> 4, cl = lane & 15;
  const int wr = wave >> 2, wc = wave & 3;      // 2M x 4N
  const int bx = blockIdx.x;                    // out cols [bx*128, +128)
  const int m0 = blockIdx.y << 8;
  const int K2 = DMODEL * 2;

  const char* pA[4];
  const char* pB[2];
#pragma unroll
  for (int i = 0; i < 4; ++i) {
    const int o = i * 8192 + tid * 16;
    const int op = o ^ (((o >> 7) & 7) << 4);
    const int row = op >> 7, colb = op & 127;
    pA[i] = (const char*)A + (size_t)(m0 + row) * K2 + colb;
  }
#pragma unroll
  for (int i = 0; i < 2; ++i) {
    const int o = i * 8192 + tid * 16;
    const int op = o ^ (((o >> 7) & 7) << 4);
    const int row = op >> 7, colb = op & 127;
    pB[i] = (const char*)Bt + (size_t)(bx * 128 + row) * K2 + colb;
  }

  int aoff[8], boff[2];
#pragma unroll
  for (int m = 0; m < 8; ++m)
    aoff[m] = (wr * 128 + m * 16 + cl) * 128 + ((g * 16) ^ ((cl & 7) << 4));
#pragma unroll
  for (int n = 0; n < 2; ++n)
    boff[n] = (wc * 32 + n * 16 + cl) * 128 + ((g * 16) ^ ((cl & 7) << 4));

  const f32x4 fz = {0.f, 0.f, 0.f, 0.f};
  f32x4 acc[8][2];
#pragma unroll
  for (int i = 0; i < 8; ++i)
#pragma unroll
    for (int j = 0; j < 2; ++j) acc[i][j] = fz;

  const int NT = DMODEL / 64;   // 32 K-tiles

  {
    u16* da = &As2[0][wave * 512];
    u16* db = &Bs2[0][wave * 512];
#pragma unroll
    for (int i = 0; i < 4; ++i) gload16(pA[i], da + i * 4096);
#pragma unroll
    for (int i = 0; i < 2; ++i) gload16(pB[i], db + i * 4096);
  }
  asm volatile("s_waitcnt vmcnt(0)" ::: "memory");
  __builtin_amdgcn_s_barrier();

  int s = 0;
#pragma unroll 1
  for (int t = 0; t < NT; ++t) {
    const char* as = (const char*)&As2[s][0];
    const char* bs = (const char*)&Bs2[s][0];
    const bool pf = (t + 1 < NT);
    const size_t ko = (size_t)(t + 1) * 128;
    u16* da = &As2[s ^ 1][wave * 512];
    u16* db = &Bs2[s ^ 1][wave * 512];

    s16x8 afr[4][2], bf_[2][2];
    // ph0: m-half 0, all n
#pragma unroll
    for (int i = 0; i < 4; ++i) {
      afr[i][0] = *(const s16x8*)(as + aoff[i]);
      afr[i][1] = *(const s16x8*)(as + (aoff[i] ^ 64));
    }
#pragma unroll
    for (int j = 0; j < 2; ++j) {
      bf_[j][0] = *(const s16x8*)(bs + boff[j]);
      bf_[j][1] = *(const s16x8*)(bs + (boff[j] ^ 64));
    }
    if (pf) {
#pragma unroll
      for (int i = 0; i < 4; ++i) gload16(pA[i] + ko, da + i * 4096);
    }
    asm volatile("s_waitcnt lgkmcnt(0)" ::: "memory");
    __builtin_amdgcn_sched_barrier(0);
    __builtin_amdgcn_s_setprio(1);
#pragma unroll
    for (int i = 0; i < 4; ++i)
#pragma unroll
      for (int j = 0; j < 2; ++j)
#pragma unroll
        for (int kk = 0; kk < 2; ++kk)
          acc[i][j] = __builtin_amdgcn_mfma_f32_16x16x32_bf16(
              afr[i][kk], bf_[j][kk], acc[i][j], 0, 0, 0);
    __builtin_amdgcn_s_setprio(0);
    // ph1: m-half 1
#pragma unroll
    for (int i = 0; i < 4; ++i) {
      afr[i][0] = *(const s16x8*)(as + aoff[4 + i]);
      afr[i][1] = *(const s16x8*)(as + (aoff[4 + i] ^ 64));
    }
    if (pf) {
#pragma unroll
      for (int i = 0; i < 2; ++i) gload16(pB[i] + ko, db + i * 4096);
    }
    asm volatile("s_waitcnt lgkmcnt(0)" ::: "memory");
    __builtin_amdgcn_sched_barrier(0);
    __builtin_amdgcn_s_setprio(1);
#pragma unroll
    for (int i = 0; i < 4; ++i)
#pragma unroll
      for (int j = 0; j < 2; ++j)
#pragma unroll
        for (int kk = 0; kk < 2; ++kk)
          acc[4 + i][j] = __builtin_amdgcn_mfma_f32_16x16x32_bf16(
              afr[i][kk], bf_[j][kk], acc[4 + i][j], 0, 0, 0);
    __builtin_amdgcn_s_setprio(0);
    if (pf) asm volatile("s_waitcnt vmcnt(0)" ::: "memory");
    __builtin_amdgcn_s_barrier();
    s ^= 1;
  }

  const int orow0 = m0 + wr * 128 + g * 4;
#pragma unroll
  for (int m = 0; m < 8; ++m)
#pragma unroll
    for (int n = 0; n < 2; ++n) {
      const int col = bx * 128 + wc * 32 + n * 16 + cl;
#pragma unroll
      for (int r = 0; r < 4; ++r) {
        const size_t idx = (size_t)(orow0 + m * 16 + r) * DMODEL + col;
        X1out[idx] = acc[m][n][r] + resid[idx];
      }
    }
}

// ---------------------------------------------------------------------------
// Combine split-K partials + residual: out = P0 + P1 + X1 (f32, float4)
// ---------------------------------------------------------------------------
__global__ __launch_bounds__(256) void add3_k(const float* __restrict__ P0,
                                              const float* __restrict__ P1,
                                              const float* __restrict__ X1,
                                              float* __restrict__ out) {
  const size_t i = (size_t)blockIdx.x * 256 + threadIdx.x;
  const float4 a = ((const float4*)P0)[i];
  const float4 b = ((const float4*)P1)[i];
  const float4 c = ((const float4*)X1)[i];
  float4 o;
  o.x = a.x + b.x + c.x;
  o.y = a.y + b.y + c.y;
  o.z = a.z + b.z + c.z;
  o.w = a.w + b.w + c.w;
  ((float4*)out)[i] = o;
}

// ---------------------------------------------------------------------------
// RoPE tables: cos/sin [S_LEN][64] f32
// ---------------------------------------------------------------------------
__global__ __launch_bounds__(256) void rope_table_k(float* __restrict__ tc,
                                                    float* __restrict__ ts) {
  const int idx = blockIdx.x * 256 + threadIdx.x;   // S_LEN*64 = 131072
  const int pos = idx >> 6, j = idx & 63;
  const float inv = expf(((float)(2 * j) * (1.0f / 128.0f)) * -logf(10000.0f));
  const float th = (float)pos * inv;
  tc[idx] = cosf(th);
  ts[idx] = sinf(th);
}

// RoPE apply — K ONLY (granule layout); Q rope is fused into attn_k.
__global__ __launch_bounds__(256) void rope_k_only(u16* __restrict__ KG,
                                                   const float* __restrict__ tc,
                                                   const float* __restrict__ ts) {
  const int idx = blockIdx.x * 256 + threadIdx.x;   // 2^22 total
  const int j = idx & 63;
  const int h = (idx >> 6) & (NHEADS - 1);
  const int row = idx >> 10;                        // 0..4095
  const int s = row & (S_LEN - 1);
  const int bh = (row >> 11) * NHEADS + h;
  const float c = tc[s * 64 + j], sn = ts[s * 64 + j];
  u16* p = KG + (size_t)(bh * 32 + (s >> 6)) * 8192 +
           ((j >> 3) * 64 + (s & 63)) * 8 + (j & 7);
  const float x1 = bf2f(p[0]);
  const float x2 = bf2f(p[4096]);
  p[0]    = f2bf(x1 * c - x2 * sn);
  p[4096] = f2bf(x2 * c + x1 * sn);
}

// ---------------------------------------------------------------------------
// Flash attention. 4 waves x 32 q-rows = 128 q/block; KVBLK=64.
// Q rope applied in-register after fragment load.
// ---------------------------------------------------------------------------
__global__ __launch_bounds__(256, 2) void attn_k(const u16* __restrict__ Q,
                                                 const u16* __restrict__ KG,
                                                 const u16* __restrict__ VG,
                                                 u16* __restrict__ O,
                                                 const float* __restrict__ TC,
                                                 const float* __restrict__ TS) {
  __shared__ __align__(16) u16 Ks[2][8192];   // 2 x 16KB (1024 granules: c*64+kv)
  __shared__ __align__(16) u16 Vs[8192];      // 16KB (1024 granules: cs*128+dh)
  __shared__ __align__(16) u16 Ps[4][2048];   // 4KB/wave (256 granules, permuted)
  const int tid = threadIdx.x, lane = tid & 63, wave = tid >> 6;
  const int g = lane >> 4, cl = lane & 15;
  const int qt = blockIdx.x, bh = blockIdx.y;
  const int b = bh >> 4, h = bh & (NHEADS - 1);
  const int qrow0 = b * S_LEN + qt * 128 + wave * 32;   // batch offset included

  // Q fragments: row = qrow0 + qs*16 + cl, d = ks*32 + g*8
  s16x8 aq[2][4];
#pragma unroll
  for (int qs = 0; qs < 2; ++qs)
#pragma unroll
    for (int ks = 0; ks < 4; ++ks)
      aq[qs][ks] = *(const s16x8*)(Q + (size_t)(qrow0 + qs * 16 + cl) * DMODEL +
                                   h * DHEAD + ks * 32 + g * 8);

  // in-register Q RoPE
#pragma unroll
  for (int qs = 0; qs < 2; ++qs) {
    const int s0 = qt * 128 + wave * 32 + qs * 16 + cl;   // seq position
    const float* tcs = TC + s0 * 64 + g * 8;
    const float* tss = TS + s0 * 64 + g * 8;
#pragma unroll
    for (int ks = 0; ks < 2; ++ks)
#pragma unroll
      for (int j = 0; j < 8; ++j) {
        const float c = tcs[ks * 32 + j];
        const float sn = tss[ks * 32 + j];
        const float x1 = bf2f((u16)aq[qs][ks][j]);
        const float x2 = bf2f((u16)aq[qs][ks + 2][j]);
        aq[qs][ks][j]     = (short)f2bf(x1 * c - x2 * sn);
        aq[qs][ks + 2][j] = (short)f2bf(x2 * c + x1 * sn);
      }
  }

  const u16* kgb = KG + (size_t)bh * 32 * 8192;
  const u16* vgb = VG + (size_t)bh * 32 * 8192;

  auto stage_k = [&](int kt, int buf) {
    const u16* sp = kgb + (size_t)kt * 8192 + wave * 2048 + lane * 8;
    u16* dp = &Ks[buf][wave * 2048];
#pragma unroll
    for (int i = 0; i < 4; ++i) gload16(sp + i * 512, dp + i * 512);
  };
  auto stage_v = [&](int kt) {
    const u16* sp = vgb + (size_t)kt * 8192 + wave * 2048 + lane * 8;
    u16* dp = &Vs[wave * 2048];
#pragma unroll
    for (int i = 0; i < 4; ++i) gload16(sp + i * 512, dp + i * 512);
  };

  const float scale = 0.08838834764831845f;  // 1/sqrt(128)
  const f32x4 fz = {0.f, 0.f, 0.f, 0.f};
  f32x4 ctx[2][8];
#pragma unroll
  for (int qs = 0; qs < 2; ++qs)
#pragma unroll
    for (int n = 0; n < 8; ++n) ctx[qs][n] = fz;
  float mx[2][4], lr[2][4];
#pragma unroll
  for (int qs = 0; qs < 2; ++qs)
#pragma unroll
    for (int r = 0; r < 4; ++r) { mx[qs][r] = -1e30f; lr[qs][r] = 0.f; }

  auto body = [&](int it, int buf, bool pref) {
    stage_v(it);
    if (pref) stage_k(it + 1, buf ^ 1);
    f32x4 s[2][4];
#pragma unroll
    for (int qs = 0; qs < 2; ++qs)
#pragma unroll
      for (int t = 0; t < 4; ++t) s[qs][t] = fz;
#pragma unroll
    for (int t = 0; t < 4; ++t) {
      s16x8 kf[4];
#pragma unroll
      for (int ks = 0; ks < 4; ++ks)
        kf[ks] = *(const s16x8*)(&Ks[buf][((ks * 4 + g) * 64 + t * 16 + cl) * 8]);
#pragma unroll
      for (int qs = 0; qs < 2; ++qs)
#pragma unroll
        for (int ks = 0; ks < 4; ++ks)
          s[qs][t] = __builtin_amdgcn_mfma_f32_16x16x32_bf16(aq[qs][ks], kf[ks],
                                                             s[qs][t], 0, 0, 0);
    }
    float corr[2][4];
#pragma unroll
    for (int qs = 0; qs < 2; ++qs)
#pragma unroll
      for (int r = 0; r < 4; ++r) {
        const float a0 = s[qs][0][r] * scale, a1 = s[qs][1][r] * scale;
        const float a2 = s[qs][2][r] * scale, a3 = s[qs][3][r] * scale;
        float v = fmaxf(fmaxf(a0, a1), fmaxf(a2, a3));
        v = red16_max(v);
        const float nm = fmaxf(mx[qs][r], v);
        const float c_ = __expf(mx[qs][r] - nm);
        mx[qs][r] = nm;
        corr[qs][r] = c_;
        const float p0 = __expf(a0 - nm), p1 = __expf(a1 - nm);
        const float p2 = __expf(a2 - nm), p3 = __expf(a3 - nm);
        float rs = (p0 + p1) + (p2 + p3);
        rs = red16_sum(rs);
        lr[qs][r] = lr[qs][r] * c_ + rs;
        const int pb = (qs * 16 + r * 4 + g) * 8 + (cl & 7) + (cl >> 3) * 256;
        Ps[wave][pb]        = f2bf(p0);
        Ps[wave][pb + 512]  = f2bf(p1);
        Ps[wave][pb + 1024] = f2bf(p2);
        Ps[wave][pb + 1536] = f2bf(p3);
      }
#pragma unroll
    for (int qs = 0; qs < 2; ++qs)
#pragma unroll
      for (int n = 0; n < 8; ++n)
#pragma unroll
        for (int r = 0; r < 4; ++r) ctx[qs][n][r] *= corr[qs][r];
    if (pref) asm volatile("s_waitcnt vmcnt(4)" ::: "memory");
    else      asm volatile("s_waitcnt vmcnt(0)" ::: "memory");
    __builtin_amdgcn_s_barrier();
    s16x8 pa[2][2];
#pragma unroll
    for (int qs = 0; qs < 2; ++qs)
#pragma unroll
      for (int k2 = 0; k2 < 2; ++k2)
        pa[qs][k2] = *(const s16x8*)(&Ps[wave][((k2 * 4 + g) * 32 + qs * 16 +
                                                (cl & 3) * 4 + (cl >> 2)) * 8]);
#pragma unroll
    for (int n = 0; n < 8; ++n) {
      s16x8 vf0 = *(const s16x8*)(&Vs[((g) * 128 + n * 16 + cl) * 8]);
      s16x8 vf1 = *(const s16x8*)(&Vs[((4 + g) * 128 + n * 16 + cl) * 8]);
#pragma unroll
      for (int qs = 0; qs < 2; ++qs) {
        ctx[qs][n] = __builtin_amdgcn_mfma_f32_16x16x32_bf16(pa[qs][0], vf0,
                                                             ctx[qs][n], 0, 0, 0);
        ctx[qs][n] = __builtin_amdgcn_mfma_f32_16x16x32_bf16(pa[qs][1], vf1,
                                                             ctx[qs][n], 0, 0, 0);
      }
    }
    asm volatile("s_waitcnt vmcnt(0)" ::: "memory");
    __builtin_amdgcn_s_barrier();
  };

  stage_k(0, 0);
  asm volatile("s_waitcnt vmcnt(0)" ::: "memory");
  __builtin_amdgcn_s_barrier();
#pragma unroll 1
  for (int it = 0; it < 31; ++it) body(it, it & 1, true);
  body(31, 1, false);

#pragma unroll
  for (int qs = 0; qs < 2; ++qs) {
    float inv[4];
#pragma unroll
    for (int r = 0; r < 4; ++r) inv[r] = 1.0f / lr[qs][r];
#pragma unroll
    for (int n = 0; n < 8; ++n)
#pragma unroll
      for (int r = 0; r < 4; ++r)
        O[(size_t)(qrow0 + qs * 16 + g * 4 + r) * DMODEL + h * DHEAD + n * 16 + cl] =
            f2bf(ctx[qs][n][r] * inv[r]);
  }
}

// ---------------------------------------------------------------------------
extern "C" void kernel_launch(void* const* d_in, const int* in_sizes, int n_in,
                              void* d_out, int out_size, void* d_ws, size_t ws_size,
                              hipStream_t stream) {
  (void)in_sizes; (void)n_in; (void)out_size; (void)ws_size;
  const float* x  = (const float*)d_in[0];
  const float* wq = (const float*)d_in[1];
  const float* wk = (const float*)d_in[2];
  const float* wv = (const float*)d_in[3];
  const float* wo = (const float*)d_in[4];
  const float* g1 = (const float*)d_in[5];
  const float* g2 = (const float*)d_in[6];
  const float* w1 = (const float*)d_in[7];
  const float* w2 = (const float*)d_in[8];   // dict order: w1, w2, w3
  const float* w3 = (const float*)d_in[9];
  float* out = (float*)d_out;

  char* ws = (char*)d_ws;
  size_t off = 0;
  auto alloc = [&](size_t bytes) -> char* {
    char* p = ws + off;
    off += (bytes + 255) & ~(size_t)255;
    return p;
  };
  u16* WQT = (u16*)alloc((size_t)DMODEL * DMODEL * 2);   //  8 MB
  u16* WKT = (u16*)alloc((size_t)DMODEL * DMODEL * 2);   //  8 MB
  u16* WVT = (u16*)alloc((size_t)DMODEL * DMODEL * 2);   //  8 MB
  u16* WOT = (u16*)alloc((size_t)DMODEL * DMODEL * 2);   //  8 MB
  u16* QB  = (u16*)alloc((size_t)NROWS * DMODEL * 2);    // 16 MB
  u16* KGb = (u16*)alloc((size_t)NROWS * DMODEL * 2);    // 16 MB (granule layout)
  u16* VGb = (u16*)alloc((size_t)NROWS * DMODEL * 2);    // 16 MB (granule layout)
  u16* W1T = (u16*)alloc((size_t)HID * DMODEL * 2);      // 32 MB
  u16* W3T = (u16*)alloc((size_t)HID * DMODEL * 2);      // 32 MB
  u16* W2T = (u16*)alloc((size_t)DMODEL * HID * 2);      // 32 MB
  u16* Hb  = (u16*)alloc((size_t)NROWS * DMODEL * 2);    // 16 MB (h1 / AO / h2)
  float* X1 = (float*)alloc((size_t)NROWS * DMODEL * 4); // 32 MB
  float* TC = (float*)alloc((size_t)S_LEN * 64 * 4);
  float* TS = (float*)alloc((size_t)S_LEN * 64 * 4);
  // U[4096][8192] bf16 = 64 MB aliases WQT..WOT+QB+KGb (all dead by then)
  u16* U = WQT;
  u16* AO = Hb;   // attention output overwrites h1 (dead after QKV GEMMs)
  // split-K partials: 2 x 32 MB f32, alias W1T+W3T (dead after gemm8_swiglu)
  float* P01 = (float*)W1T;

  const dim3 b256(256);
  const dim3 tb(32, 8);

  rope_table_k<<<dim3(512), b256, 0, stream>>>(TC, TS);
  transpose_cvt<<<dim3(64, 64), tb, 0, stream>>>(wq, WQT, DMODEL, DMODEL);
  transpose_cvt<<<dim3(64, 64), tb, 0, stream>>>(wk, WKT, DMODEL, DMODEL);
  transpose_cvt<<<dim3(64, 64), tb, 0, stream>>>(wv, WVT, DMODEL, DMODEL);
  transpose_cvt<<<dim3(64, 64), tb, 0, stream>>>(wo, WOT, DMODEL, DMODEL);
  transpose_cvt<<<dim3(256, 64), tb, 0, stream>>>(w1, W1T, DMODEL, HID);
  transpose_cvt<<<dim3(256, 64), tb, 0, stream>>>(w3, W3T, DMODEL, HID);
  transpose_cvt<<<dim3(64, 256), tb, 0, stream>>>(w2, W2T, HID, DMODEL);

  rmsnorm_k<<<dim3(NROWS), b256, 0, stream>>>(x, g1, Hb);
  gemm8_qkv<<<dim3(16, 16, 3), dim3(512), 0, stream>>>(Hb, WQT, WKT, WVT,
                                                       QB, KGb, VGb);
  rope_k_only<<<dim3(16384), b256, 0, stream>>>(KGb, TC, TS);
  attn_k<<<dim3(16, 32), b256, 0, stream>>>(QB, KGb, VGb, AO, TC, TS);
  gemm8_wo<<<dim3(16, 16), dim3(512), 0, stream>>>(AO, WOT, x, X1);

  rmsnorm_k<<<dim3(NROWS), b256, 0, stream>>>(X1, g2, Hb);
  gemm8_swiglu<<<dim3(64, 16), dim3(512), 0, stream>>>(Hb, W1T, W3T, U);
  gemm8_down<<<dim3(8, 16, 2), dim3(512), 0, stream>>>(U, W2T, P01);
  add3_k<<<dim3(NROWS * DMODEL / 4 / 256), b256, 0, stream>>>(
      P01, P01 + (size_t)NROWS * DMODEL, X1, out);
}

// Round 17
// 811.951 us; speedup vs baseline: 1.0239x; 1.0239x over previous
//
#include <hip/hip_runtime.h>
#include <hip/hip_bf16.h>
#include <stdint.h>

#define S_LEN  2048
#define DMODEL 2048
#define NBATCH 2
#define NHEADS 16
#define DHEAD  128
#define HID    8192
#define NROWS  4096   // NBATCH * S_LEN

typedef unsigned short u16;
typedef unsigned int   u32;
typedef __attribute__((ext_vector_type(8))) short s16x8;   // 8 bf16 = MFMA A/B frag
typedef __attribute__((ext_vector_type(4))) float f32x4;   // MFMA C/D frag

static __device__ __forceinline__ float bf2f(u16 b) {
  return __uint_as_float(((u32)b) << 16);
}
static __device__ __forceinline__ u16 f2bf(float f) {
  u32 u = __float_as_uint(f);
  return (u16)((u + 0x7fffu + ((u >> 16) & 1u)) >> 16);   // RNE
}

// async global->LDS, 16B per lane
static __device__ __forceinline__ void gload16(const void* gp, void* lp) {
  __builtin_amdgcn_global_load_lds(
      (const __attribute__((address_space(1))) void*)gp,
      (__attribute__((address_space(3))) void*)lp, 16, 0, 0);
}

// 16-lane (DPP row) rotate-butterfly reductions — VALU pipe, no LDS traffic
#define DPP_ROR(v, C) \
  __int_as_float(__builtin_amdgcn_update_dpp(0, __float_as_int(v), C, 0xf, 0xf, true))
static __device__ __forceinline__ float red16_max(float v) {
  v = fmaxf(v, DPP_ROR(v, 0x121));
  v = fmaxf(v, DPP_ROR(v, 0x122));
  v = fmaxf(v, DPP_ROR(v, 0x124));
  v = fmaxf(v, DPP_ROR(v, 0x128));
  return v;
}
static __device__ __forceinline__ float red16_sum(float v) {
  v += DPP_ROR(v, 0x121);
  v += DPP_ROR(v, 0x122);
  v += DPP_ROR(v, 0x124);
  v += DPP_ROR(v, 0x128);
  return v;
}

// ---------------------------------------------------------------------------
// Weight prep: W[K][N] f32 -> Wt[N][K] bf16. Write-vectorized (ushort4/thread).
// ---------------------------------------------------------------------------
__global__ __launch_bounds__(256) void transpose_cvt(const float* __restrict__ W,
                                                     u16* __restrict__ Wt,
                                                     int K, int N) {
  __shared__ float tile[32][33];
  const int tx = threadIdx.x, ty = threadIdx.y;       // 32 x 8
  const int n0 = blockIdx.x * 32, k0 = blockIdx.y * 32;
#pragma unroll
  for (int i = 0; i < 4; ++i)
    tile[ty + i * 8][tx] = W[(size_t)(k0 + ty + i * 8) * N + n0 + tx];
  __syncthreads();
  const int t = ty * 32 + tx;
  const int n = t >> 3, k4 = (t & 7) * 4;             // 8 threads span one n-row
  ushort4 o;
  o.x = f2bf(tile[k4 + 0][n]);
  o.y = f2bf(tile[k4 + 1][n]);
  o.z = f2bf(tile[k4 + 2][n]);
  o.w = f2bf(tile[k4 + 3][n]);
  *(ushort4*)&Wt[(size_t)(n0 + n) * K + k0 + k4] = o;
}

// ---------------------------------------------------------------------------
// RMSNorm: row of f32 [DMODEL] -> bf16, one block per row
// ---------------------------------------------------------------------------
__global__ __launch_bounds__(256) void rmsnorm_k(const float* __restrict__ x,
                                                 const float* __restrict__ g,
                                                 u16* __restrict__ out) {
  const int row = blockIdx.x;
  const int tid = threadIdx.x;
  const float4* xr = (const float4*)(x + (size_t)row * DMODEL);
  float4 v0 = xr[tid];
  float4 v1 = xr[tid + 256];
  float ss = v0.x * v0.x + v0.y * v0.y + v0.z * v0.z + v0.w * v0.w +
             v1.x * v1.x + v1.y * v1.y + v1.z * v1.z + v1.w * v1.w;
#pragma unroll
  for (int o = 1; o < 64; o <<= 1) ss += __shfl_xor(ss, o);
  __shared__ float red[4];
  if ((tid & 63) == 0) red[tid >> 6] = ss;
  __syncthreads();
  const float tot = red[0] + red[1] + red[2] + red[3];
  const float rms = rsqrtf(tot * (1.0f / DMODEL) + 1e-6f);
  const float4* gr = (const float4*)g;
  float4 g0 = gr[tid], g1 = gr[tid + 256];
  ushort4 o0, o1;
  o0.x = f2bf(v0.x * rms * g0.x); o0.y = f2bf(v0.y * rms * g0.y);
  o0.z = f2bf(v0.z * rms * g0.z); o0.w = f2bf(v0.w * rms * g0.w);
  o1.x = f2bf(v1.x * rms * g1.x); o1.y = f2bf(v1.y * rms * g1.y);
  o1.z = f2bf(v1.z * rms * g1.z); o1.w = f2bf(v1.w * rms * g1.w);
  ushort4* orow = (ushort4*)(out + (size_t)row * DMODEL);
  orow[tid] = o0;
  orow[tid + 256] = o1;
}

// ---------------------------------------------------------------------------
// Pipelined fused SwiGLU GEMM — ONE barrier per K-tile (r15-proven).
// ---------------------------------------------------------------------------
__global__ __launch_bounds__(512, 1) void gemm8_swiglu(const u16* __restrict__ A,
                                                       const u16* __restrict__ B1t,
                                                       const u16* __restrict__ B3t,
                                                       u16* __restrict__ U) {
  __shared__ __align__(16) u16 As2[2][16384];   // 2 x 32 KB ([256 r][64 k])
  __shared__ __align__(16) u16 Bs2[2][16384];   // 2 x 32 KB ([256 br][64 k])
  const int tid = threadIdx.x;
  const int lane = tid & 63, wave = tid >> 6;
  const int g = lane >> 4, cl = lane & 15;
  const int wr = wave >> 2, wc = wave & 3;      // 2M x 4N
  const int bx = blockIdx.x;                    // U cols [bx*128, +128)
  const int m0 = blockIdx.y << 8;               // A rows [m0, m0+256)
  const int K2 = DMODEL * 2;                    // row stride in bytes

  const char* pA[4];
  const char* pB[4];
#pragma unroll
  for (int i = 0; i < 4; ++i) {
    const int o = i * 8192 + tid * 16;          // byte offset in 32KB tile
    const int op = o ^ (((o >> 7) & 7) << 4);
    const int row = op >> 7, colb = op & 127;
    pA[i] = (const char*)A + (size_t)(m0 + row) * K2 + colb;
    const int pl = row >> 5, half = (row >> 4) & 1, c = row & 15;
    const int grow = bx * 128 + pl * 16 + c;
    pB[i] = (const char*)(half ? B3t : B1t) + (size_t)grow * K2 + colb;
  }

  int aoff[8], boff[4];
#pragma unroll
  for (int m = 0; m < 8; ++m)
    aoff[m] = (wr * 128 + m * 16 + cl) * 128 + ((g * 16) ^ ((cl & 7) << 4));
#pragma unroll
  for (int n = 0; n < 4; ++n)
    boff[n] = (wc * 64 + n * 16 + cl) * 128 + ((g * 16) ^ ((cl & 7) << 4));

  const f32x4 fz = {0.f, 0.f, 0.f, 0.f};
  f32x4 acc[8][4];
#pragma unroll
  for (int i = 0; i < 8; ++i)
#pragma unroll
    for (int j = 0; j < 4; ++j) acc[i][j] = fz;

  const int NT = DMODEL / 64;   // 32 K-tiles

  {
    u16* da = &As2[0][wave * 512];
    u16* db = &Bs2[0][wave * 512];
#pragma unroll
    for (int i = 0; i < 4; ++i) gload16(pA[i], da + i * 4096);
#pragma unroll
    for (int i = 0; i < 4; ++i) gload16(pB[i], db + i * 4096);
  }
  asm volatile("s_waitcnt vmcnt(0)" ::: "memory");
  __builtin_amdgcn_s_barrier();

  int s = 0;
#pragma unroll 1
  for (int t = 0; t < NT; ++t) {
    const char* as = (const char*)&As2[s][0];
    const char* bs = (const char*)&Bs2[s][0];
    const bool pf = (t + 1 < NT);
    const size_t ko = (size_t)(t + 1) * 128;
    u16* da = &As2[s ^ 1][wave * 512];
    u16* db = &Bs2[s ^ 1][wave * 512];

    s16x8 afr[4][2], bf0[2][2], bf1[2][2];
    // ph0 (m0,n0)
#pragma unroll
    for (int i = 0; i < 4; ++i) {
      afr[i][0] = *(const s16x8*)(as + aoff[i]);
      afr[i][1] = *(const s16x8*)(as + (aoff[i] ^ 64));
    }
#pragma unroll
    for (int j = 0; j < 2; ++j) {
      bf0[j][0] = *(const s16x8*)(bs + boff[j]);
      bf0[j][1] = *(const s16x8*)(bs + (boff[j] ^ 64));
    }
    if (pf) {
#pragma unroll
      for (int i = 0; i < 4; ++i) gload16(pA[i] + ko, da + i * 4096);
    }
    asm volatile("s_waitcnt lgkmcnt(0)" ::: "memory");
    __builtin_amdgcn_sched_barrier(0);
    __builtin_amdgcn_s_setprio(1);
#pragma unroll
    for (int i = 0; i < 4; ++i)
#pragma unroll
      for (int j = 0; j < 2; ++j)
#pragma unroll
        for (int kk = 0; kk < 2; ++kk)
          acc[i][j] = __builtin_amdgcn_mfma_f32_16x16x32_bf16(
              afr[i][kk], bf0[j][kk], acc[i][j], 0, 0, 0);
    __builtin_amdgcn_s_setprio(0);
    // ph1 (m0,n1)
#pragma unroll
    for (int j = 0; j < 2; ++j) {
      bf1[j][0] = *(const s16x8*)(bs + boff[2 + j]);
      bf1[j][1] = *(const s16x8*)(bs + (boff[2 + j] ^ 64));
    }
    if (pf) {
#pragma unroll
      for (int i = 0; i < 4; ++i) gload16(pB[i] + ko, db + i * 4096);
    }
    asm volatile("s_waitcnt lgkmcnt(0)" ::: "memory");
    __builtin_amdgcn_sched_barrier(0);
    __builtin_amdgcn_s_setprio(1);
#pragma unroll
    for (int i = 0; i < 4; ++i)
#pragma unroll
      for (int j = 0; j < 2; ++j)
#pragma unroll
        for (int kk = 0; kk < 2; ++kk)
          acc[i][2 + j] = __builtin_amdgcn_mfma_f32_16x16x32_bf16(
              afr[i][kk], bf1[j][kk], acc[i][2 + j], 0, 0, 0);
    __builtin_amdgcn_s_setprio(0);
    // ph2 (m1,n1)
#pragma unroll
    for (int i = 0; i < 4; ++i) {
      afr[i][0] = *(const s16x8*)(as + aoff[4 + i]);
      afr[i][1] = *(const s16x8*)(as + (aoff[4 + i] ^ 64));
    }
    asm volatile("s_waitcnt lgkmcnt(0)" ::: "memory");
    __builtin_amdgcn_sched_barrier(0);
    __builtin_amdgcn_s_setprio(1);
#pragma unroll
    for (int i = 0; i < 4; ++i)
#pragma unroll
      for (int j = 0; j < 2; ++j)
#pragma unroll
        for (int kk = 0; kk < 2; ++kk)
          acc[4 + i][2 + j] = __builtin_amdgcn_mfma_f32_16x16x32_bf16(
              afr[i][kk], bf1[j][kk], acc[4 + i][2 + j], 0, 0, 0);
    __builtin_amdgcn_s_setprio(0);
    // ph3 (m1,n0) — pure MFMA
    __builtin_amdgcn_s_setprio(1);
#pragma unroll
    for (int i = 0; i < 4; ++i)
#pragma unroll
      for (int j = 0; j < 2; ++j)
#pragma unroll
        for (int kk = 0; kk < 2; ++kk)
          acc[4 + i][j] = __builtin_amdgcn_mfma_f32_16x16x32_bf16(
              afr[i][kk], bf0[j][kk], acc[4 + i][j], 0, 0, 0);
    __builtin_amdgcn_s_setprio(0);
    if (pf) asm volatile("s_waitcnt vmcnt(0)" ::: "memory");
    __builtin_amdgcn_s_barrier();
    s ^= 1;
  }

  const int orow0 = m0 + wr * 128 + g * 4;
#pragma unroll
  for (int m = 0; m < 8; ++m)
#pragma unroll
    for (int p = 0; p < 2; ++p) {
      const int col = bx * 128 + wc * 32 + p * 16 + cl;
      const f32x4 a1 = acc[m][p * 2];
      const f32x4 a3 = acc[m][p * 2 + 1];
#pragma unroll
      for (int r = 0; r < 4; ++r) {
        const float a = a1[r];
        const float v = (a / (1.f + __expf(-a))) * a3[r];
        U[(size_t)(orow0 + m * 16 + r) * HID + col] = f2bf(v);
      }
    }
}

// ---------------------------------------------------------------------------
// Pipelined down-projection GEMM, split-K=2 — one barrier per K-tile.
// ---------------------------------------------------------------------------
__global__ __launch_bounds__(512, 1) void gemm8_down(const u16* __restrict__ A,
                                                     const u16* __restrict__ Bt,
                                                     float* __restrict__ P) {
  __shared__ __align__(16) u16 As2[2][16384];
  __shared__ __align__(16) u16 Bs2[2][16384];
  const int tid = threadIdx.x;
  const int lane = tid & 63, wave = tid >> 6;
  const int g = lane >> 4, cl = lane & 15;
  const int wr = wave >> 2, wc = wave & 3;
  const int bx = blockIdx.x;
  const int m0 = blockIdx.y << 8;
  const int kz = blockIdx.z;
  const int K2 = HID * 2;
  const size_t kzoff = (size_t)kz * 4096 * 2;

  const char* pA[4];
  const char* pB[4];
#pragma unroll
  for (int i = 0; i < 4; ++i) {
    const int o = i * 8192 + tid * 16;
    const int op = o ^ (((o >> 7) & 7) << 4);
    const int row = op >> 7, colb = op & 127;
    pA[i] = (const char*)A + (size_t)(m0 + row) * K2 + colb + kzoff;
    pB[i] = (const char*)Bt + (size_t)(bx * 256 + row) * K2 + colb + kzoff;
  }

  int aoff[8], boff[4];
#pragma unroll
  for (int m = 0; m < 8; ++m)
    aoff[m] = (wr * 128 + m * 16 + cl) * 128 + ((g * 16) ^ ((cl & 7) << 4));
#pragma unroll
  for (int n = 0; n < 4; ++n)
    boff[n] = (wc * 64 + n * 16 + cl) * 128 + ((g * 16) ^ ((cl & 7) << 4));

  const f32x4 fz = {0.f, 0.f, 0.f, 0.f};
  f32x4 acc[8][4];
#pragma unroll
  for (int i = 0; i < 8; ++i)
#pragma unroll
    for (int j = 0; j < 4; ++j) acc[i][j] = fz;

  const int NT = 4096 / 64;

  {
    u16* da = &As2[0][wave * 512];
    u16* db = &Bs2[0][wave * 512];
#pragma unroll
    for (int i = 0; i < 4; ++i) gload16(pA[i], da + i * 4096);
#pragma unroll
    for (int i = 0; i < 4; ++i) gload16(pB[i], db + i * 4096);
  }
  asm volatile("s_waitcnt vmcnt(0)" ::: "memory");
  __builtin_amdgcn_s_barrier();

  int s = 0;
#pragma unroll 1
  for (int t = 0; t < NT; ++t) {
    const char* as = (const char*)&As2[s][0];
    const char* bs = (const char*)&Bs2[s][0];
    const bool pf = (t + 1 < NT);
    const size_t ko = (size_t)(t + 1) * 128;
    u16* da = &As2[s ^ 1][wave * 512];
    u16* db = &Bs2[s ^ 1][wave * 512];

    s16x8 afr[4][2], bf0[2][2], bf1[2][2];
    // ph0
#pragma unroll
    for (int i = 0; i < 4; ++i) {
      afr[i][0] = *(const s16x8*)(as + aoff[i]);
      afr[i][1] = *(const s16x8*)(as + (aoff[i] ^ 64));
    }
#pragma unroll
    for (int j = 0; j < 2; ++j) {
      bf0[j][0] = *(const s16x8*)(bs + boff[j]);
      bf0[j][1] = *(const s16x8*)(bs + (boff[j] ^ 64));
    }
    if (pf) {
#pragma unroll
      for (int i = 0; i < 4; ++i) gload16(pA[i] + ko, da + i * 4096);
    }
    asm volatile("s_waitcnt lgkmcnt(0)" ::: "memory");
    __builtin_amdgcn_sched_barrier(0);
    __builtin_amdgcn_s_setprio(1);
#pragma unroll
    for (int i = 0; i < 4; ++i)
#pragma unroll
      for (int j = 0; j < 2; ++j)
#pragma unroll
        for (int kk = 0; kk < 2; ++kk)
          acc[i][j] = __builtin_amdgcn_mfma_f32_16x16x32_bf16(
              afr[i][kk], bf0[j][kk], acc[i][j], 0, 0, 0);
    __builtin_amdgcn_s_setprio(0);
    // ph1
#pragma unroll
    for (int j = 0; j < 2; ++j) {
      bf1[j][0] = *(const s16x8*)(bs + boff[2 + j]);
      bf1[j][1] = *(const s16x8*)(bs + (boff[2 + j] ^ 64));
    }
    if (pf) {
#pragma unroll
      for (int i = 0; i < 4; ++i) gload16(pB[i] + ko, db + i * 4096);
    }
    asm volatile("s_waitcnt lgkmcnt(0)" ::: "memory");
    __builtin_amdgcn_sched_barrier(0);
    __builtin_amdgcn_s_setprio(1);
#pragma unroll
    for (int i = 0; i < 4; ++i)
#pragma unroll
      for (int j = 0; j < 2; ++j)
#pragma unroll
        for (int kk = 0; kk < 2; ++kk)
          acc[i][2 + j] = __builtin_amdgcn_mfma_f32_16x16x32_bf16(
              afr[i][kk], bf1[j][kk], acc[i][2 + j], 0, 0, 0);
    __builtin_amdgcn_s_setprio(0);
    // ph2
#pragma unroll
    for (int i = 0; i < 4; ++i) {
      afr[i][0] = *(const s16x8*)(as + aoff[4 + i]);
      afr[i][1] = *(const s16x8*)(as + (aoff[4 + i] ^ 64));
    }
    asm volatile("s_waitcnt lgkmcnt(0)" ::: "memory");
    __builtin_amdgcn_sched_barrier(0);
    __builtin_amdgcn_s_setprio(1);
#pragma unroll
    for (int i = 0; i < 4; ++i)
#pragma unroll
      for (int j = 0; j < 2; ++j)
#pragma unroll
        for (int kk = 0; kk < 2; ++kk)
          acc[4 + i][2 + j] = __builtin_amdgcn_mfma_f32_16x16x32_bf16(
              afr[i][kk], bf1[j][kk], acc[4 + i][2 + j], 0, 0, 0);
    __builtin_amdgcn_s_setprio(0);
    // ph3
    __builtin_amdgcn_s_setprio(1);
#pragma unroll
    for (int i = 0; i < 4; ++i)
#pragma unroll
      for (int j = 0; j < 2; ++j)
#pragma unroll
        for (int kk = 0; kk < 2; ++kk)
          acc[4 + i][j] = __builtin_amdgcn_mfma_f32_16x16x32_bf16(
              afr[i][kk], bf0[j][kk], acc[4 + i][j], 0, 0, 0);
    __builtin_amdgcn_s_setprio(0);
    if (pf) asm volatile("s_waitcnt vmcnt(0)" ::: "memory");
    __builtin_amdgcn_s_barrier();
    s ^= 1;
  }

  float* Pz = P + (size_t)kz * NROWS * DMODEL;
  const int orow0 = m0 + wr * 128 + g * 4;
#pragma unroll
  for (int m = 0; m < 8; ++m)
#pragma unroll
    for (int n = 0; n < 4; ++n) {
      const int col = bx * 256 + wc * 64 + n * 16 + cl;
#pragma unroll
      for (int r = 0; r < 4; ++r)
        Pz[(size_t)(orow0 + m * 16 + r) * DMODEL + col] = acc[m][n][r];
    }
}

// ---------------------------------------------------------------------------
// Fused QKV GEMM — r15-proven BN=256 body, grid (8,16,3), one barrier/tile.
// z=0: Q row layout; z=1: K granule; z=2: V granule.
// ---------------------------------------------------------------------------
__global__ __launch_bounds__(512, 1) void gemm8_qkv(const u16* __restrict__ A,
                                                    const u16* __restrict__ WQ,
                                                    const u16* __restrict__ WK,
                                                    const u16* __restrict__ WV,
                                                    u16* __restrict__ QB,
                                                    u16* __restrict__ KG,
                                                    u16* __restrict__ VG) {
  __shared__ __align__(16) u16 As2[2][16384];
  __shared__ __align__(16) u16 Bs2[2][16384];
  const int tid = threadIdx.x;
  const int lane = tid & 63, wave = tid >> 6;
  const int g = lane >> 4, cl = lane & 15;
  const int wr = wave >> 2, wc = wave & 3;
  const int bx = blockIdx.x;                    // out cols [bx*256, +256)
  const int m0 = blockIdx.y << 8;
  const int z = blockIdx.z;                     // 0=Q 1=K 2=V
  const int K2 = DMODEL * 2;
  const u16* Bt = (z == 0) ? WQ : (z == 1) ? WK : WV;

  const char* pA[4];
  const char* pB[4];
#pragma unroll
  for (int i = 0; i < 4; ++i) {
    const int o = i * 8192 + tid * 16;
    const int op = o ^ (((o >> 7) & 7) << 4);
    const int row = op >> 7, colb = op & 127;
    pA[i] = (const char*)A + (size_t)(m0 + row) * K2 + colb;
    pB[i] = (const char*)Bt + (size_t)(bx * 256 + row) * K2 + colb;
  }

  int aoff[8], boff[4];
#pragma unroll
  for (int m = 0; m < 8; ++m)
    aoff[m] = (wr * 128 + m * 16 + cl) * 128 + ((g * 16) ^ ((cl & 7) << 4));
#pragma unroll
  for (int n = 0; n < 4; ++n)
    boff[n] = (wc * 64 + n * 16 + cl) * 128 + ((g * 16) ^ ((cl & 7) << 4));

  const f32x4 fz = {0.f, 0.f, 0.f, 0.f};
  f32x4 acc[8][4];
#pragma unroll
  for (int i = 0; i < 8; ++i)
#pragma unroll
    for (int j = 0; j < 4; ++j) acc[i][j] = fz;

  const int NT = DMODEL / 64;   // 32 K-tiles

  {
    u16* da = &As2[0][wave * 512];
    u16* db = &Bs2[0][wave * 512];
#pragma unroll
    for (int i = 0; i < 4; ++i) gload16(pA[i], da + i * 4096);
#pragma unroll
    for (int i = 0; i < 4; ++i) gload16(pB[i], db + i * 4096);
  }
  asm volatile("s_waitcnt vmcnt(0)" ::: "memory");
  __builtin_amdgcn_s_barrier();

  int s = 0;
#pragma unroll 1
  for (int t = 0; t < NT; ++t) {
    const char* as = (const char*)&As2[s][0];
    const char* bs = (const char*)&Bs2[s][0];
    const bool pf = (t + 1 < NT);
    const size_t ko = (size_t)(t + 1) * 128;
    u16* da = &As2[s ^ 1][wave * 512];
    u16* db = &Bs2[s ^ 1][wave * 512];

    s16x8 afr[4][2], bf0[2][2], bf1[2][2];
    // ph0
#pragma unroll
    for (int i = 0; i < 4; ++i) {
      afr[i][0] = *(const s16x8*)(as + aoff[i]);
      afr[i][1] = *(const s16x8*)(as + (aoff[i] ^ 64));
    }
#pragma unroll
    for (int j = 0; j < 2; ++j) {
      bf0[j][0] = *(const s16x8*)(bs + boff[j]);
      bf0[j][1] = *(const s16x8*)(bs + (boff[j] ^ 64));
    }
    if (pf) {
#pragma unroll
      for (int i = 0; i < 4; ++i) gload16(pA[i] + ko, da + i * 4096);
    }
    asm volatile("s_waitcnt lgkmcnt(0)" ::: "memory");
    __builtin_amdgcn_sched_barrier(0);
    __builtin_amdgcn_s_setprio(1);
#pragma unroll
    for (int i = 0; i < 4; ++i)
#pragma unroll
      for (int j = 0; j < 2; ++j)
#pragma unroll
        for (int kk = 0; kk < 2; ++kk)
          acc[i][j] = __builtin_amdgcn_mfma_f32_16x16x32_bf16(
              afr[i][kk], bf0[j][kk], acc[i][j], 0, 0, 0);
    __builtin_amdgcn_s_setprio(0);
    // ph1
#pragma unroll
    for (int j = 0; j < 2; ++j) {
      bf1[j][0] = *(const s16x8*)(bs + boff[2 + j]);
      bf1[j][1] = *(const s16x8*)(bs + (boff[2 + j] ^ 64));
    }
    if (pf) {
#pragma unroll
      for (int i = 0; i < 4; ++i) gload16(pB[i] + ko, db + i * 4096);
    }
    asm volatile("s_waitcnt lgkmcnt(0)" ::: "memory");
    __builtin_amdgcn_sched_barrier(0);
    __builtin_amdgcn_s_setprio(1);
#pragma unroll
    for (int i = 0; i < 4; ++i)
#pragma unroll
      for (int j = 0; j < 2; ++j)
#pragma unroll
        for (int kk = 0; kk < 2; ++kk)
          acc[i][2 + j] = __builtin_amdgcn_mfma_f32_16x16x32_bf16(
              afr[i][kk], bf1[j][kk], acc[i][2 + j], 0, 0, 0);
    __builtin_amdgcn_s_setprio(0);
    // ph2
#pragma unroll
    for (int i = 0; i < 4; ++i) {
      afr[i][0] = *(const s16x8*)(as + aoff[4 + i]);
      afr[i][1] = *(const s16x8*)(as + (aoff[4 + i] ^ 64));
    }
    asm volatile("s_waitcnt lgkmcnt(0)" ::: "memory");
    __builtin_amdgcn_sched_barrier(0);
    __builtin_amdgcn_s_setprio(1);
#pragma unroll
    for (int i = 0; i < 4; ++i)
#pragma unroll
      for (int j = 0; j < 2; ++j)
#pragma unroll
        for (int kk = 0; kk < 2; ++kk)
          acc[4 + i][2 + j] = __builtin_amdgcn_mfma_f32_16x16x32_bf16(
              afr[i][kk], bf1[j][kk], acc[4 + i][2 + j], 0, 0, 0);
    __builtin_amdgcn_s_setprio(0);
    // ph3
    __builtin_amdgcn_s_setprio(1);
#pragma unroll
    for (int i = 0; i < 4; ++i)
#pragma unroll
      for (int j = 0; j < 2; ++j)
#pragma unroll
        for (int kk = 0; kk < 2; ++kk)
          acc[4 + i][j] = __builtin_amdgcn_mfma_f32_16x16x32_bf16(
              afr[i][kk], bf0[j][kk], acc[4 + i][j], 0, 0, 0);
    __builtin_amdgcn_s_setprio(0);
    if (pf) asm volatile("s_waitcnt vmcnt(0)" ::: "memory");
    __builtin_amdgcn_s_barrier();
    s ^= 1;
  }

  // ---- epilogues (C/D layout: col=lane&15, row=(lane>>4)*4+reg) ----
  const int orow0 = m0 + wr * 128 + g * 4;
  if (z == 0) {
#pragma unroll
    for (int m = 0; m < 8; ++m)
#pragma unroll
      for (int n = 0; n < 4; ++n) {
        const int col = bx * 256 + wc * 64 + n * 16 + cl;
#pragma unroll
        for (int r = 0; r < 4; ++r)
          QB[(size_t)(orow0 + m * 16 + r) * DMODEL + col] = f2bf(acc[m][n][r]);
      }
  } else if (z == 1) {
#pragma unroll
    for (int m = 0; m < 8; ++m) {
      const int row0 = orow0 + m * 16;
      const int b = row0 >> 11, s0 = row0 & 2047;
#pragma unroll
      for (int n = 0; n < 4; ++n) {
        const int col = bx * 256 + wc * 64 + n * 16 + cl;
        const int hh = col >> 7, dd = col & 127;
        u16* pg = KG + (size_t)((b * NHEADS + hh) * 32 + (s0 >> 6)) * 8192 +
                  ((dd >> 3) * 64 + (s0 & 63)) * 8 + (dd & 7);
#pragma unroll
        for (int r = 0; r < 4; ++r) pg[r * 8] = f2bf(acc[m][n][r]);
      }
    }
  } else {
#pragma unroll
    for (int m = 0; m < 8; ++m) {
      const int row0 = orow0 + m * 16;
      const int b = row0 >> 11, s0 = row0 & 2047;
#pragma unroll
      for (int n = 0; n < 4; ++n) {
        const int col = bx * 256 + wc * 64 + n * 16 + cl;
        const int hh = col >> 7, dd = col & 127;
        ushort4 o;
        o.x = f2bf(acc[m][n][0]); o.y = f2bf(acc[m][n][1]);
        o.z = f2bf(acc[m][n][2]); o.w = f2bf(acc[m][n][3]);
        *(ushort4*)(VG + (size_t)((b * NHEADS + hh) * 32 + (s0 >> 6)) * 8192 +
                    (((s0 & 63) >> 3) * 128 + dd) * 8 + (s0 & 7)) = o;
      }
    }
  }
}

// ---------------------------------------------------------------------------
// Pipelined wo projection: X1 = AO·WOt^T + x. (r15-proven, stride fix in)
// ---------------------------------------------------------------------------
__global__ __launch_bounds__(512, 1) void gemm8_wo(const u16* __restrict__ A,
                                                   const u16* __restrict__ Bt,
                                                   const float* __restrict__ resid,
                                                   float* __restrict__ X1out) {
  __shared__ __align__(16) u16 As2[2][16384];   // 2 x 32 KB (256 rows)
  __shared__ __align__(16) u16 Bs2[2][8192];    // 2 x 16 KB (128 rows)
  const int tid = threadIdx.x;
  const int lane = tid & 63, wave = tid >> 6;
  const int g = lane >> 4, cl = lane & 15;
  const int wr = wave >> 2, wc = wave & 3;      // 2M x 4N
  const int bx = blockIdx.x;                    // out cols [bx*128, +128)
  const int m0 = blockIdx.y << 8;
  const int K2 = DMODEL * 2;

  const char* pA[4];
  const char* pB[2];
#pragma unroll
  for (int i = 0; i < 4; ++i) {
    const int o = i * 8192 + tid * 16;
    const int op = o ^ (((o >> 7) & 7) << 4);
    const int row = op >> 7, colb = op & 127;
    pA[i] = (const char*)A + (size_t)(m0 + row) * K2 + colb;
  }
#pragma unroll
  for (int i = 0; i < 2; ++i) {
    const int o = i * 8192 + tid * 16;
    const int op = o ^ (((o >> 7) & 7) << 4);
    const int row = op >> 7, colb = op & 127;
    pB[i] = (const char*)Bt + (size_t)(bx * 128 + row) * K2 + colb;
  }

  int aoff[8], boff[2];
#pragma unroll
  for (int m = 0; m < 8; ++m)
    aoff[m] = (wr * 128 + m * 16 + cl) * 128 + ((g * 16) ^ ((cl & 7) << 4));
#pragma unroll
  for (int n = 0; n < 2; ++n)
    boff[n] = (wc * 32 + n * 16 + cl) * 128 + ((g * 16) ^ ((cl & 7) << 4));

  const f32x4 fz = {0.f, 0.f, 0.f, 0.f};
  f32x4 acc[8][2];
#pragma unroll
  for (int i = 0; i < 8; ++i)
#pragma unroll
    for (int j = 0; j < 2; ++j) acc[i][j] = fz;

  const int NT = DMODEL / 64;   // 32 K-tiles

  {
    u16* da = &As2[0][wave * 512];
    u16* db = &Bs2[0][wave * 512];
#pragma unroll
    for (int i = 0; i < 4; ++i) gload16(pA[i], da + i * 4096);
#pragma unroll
    for (int i = 0; i < 2; ++i) gload16(pB[i], db + i * 4096);
  }
  asm volatile("s_waitcnt vmcnt(0)" ::: "memory");
  __builtin_amdgcn_s_barrier();

  int s = 0;
#pragma unroll 1
  for (int t = 0; t < NT; ++t) {
    const char* as = (const char*)&As2[s][0];
    const char* bs = (const char*)&Bs2[s][0];
    const bool pf = (t + 1 < NT);
    const size_t ko = (size_t)(t + 1) * 128;
    u16* da = &As2[s ^ 1][wave * 512];
    u16* db = &Bs2[s ^ 1][wave * 512];

    s16x8 afr[4][2], bf_[2][2];
    // ph0: m-half 0, all n
#pragma unroll
    for (int i = 0; i < 4; ++i) {
      afr[i][0] = *(const s16x8*)(as + aoff[i]);
      afr[i][1] = *(const s16x8*)(as + (aoff[i] ^ 64));
    }
#pragma unroll
    for (int j = 0; j < 2; ++j) {
      bf_[j][0] = *(const s16x8*)(bs + boff[j]);
      bf_[j][1] = *(const s16x8*)(bs + (boff[j] ^ 64));
    }
    if (pf) {
#pragma unroll
      for (int i = 0; i < 4; ++i) gload16(pA[i] + ko, da + i * 4096);
    }
    asm volatile("s_waitcnt lgkmcnt(0)" ::: "memory");
    __builtin_amdgcn_sched_barrier(0);
    __builtin_amdgcn_s_setprio(1);
#pragma unroll
    for (int i = 0; i < 4; ++i)
#pragma unroll
      for (int j = 0; j < 2; ++j)
#pragma unroll
        for (int kk = 0; kk < 2; ++kk)
          acc[i][j] = __builtin_amdgcn_mfma_f32_16x16x32_bf16(
              afr[i][kk], bf_[j][kk], acc[i][j], 0, 0, 0);
    __builtin_amdgcn_s_setprio(0);
    // ph1: m-half 1
#pragma unroll
    for (int i = 0; i < 4; ++i) {
      afr[i][0] = *(const s16x8*)(as + aoff[4 + i]);
      afr[i][1] = *(const s16x8*)(as + (aoff[4 + i] ^ 64));
    }
    if (pf) {
#pragma unroll
      for (int i = 0; i < 2; ++i) gload16(pB[i] + ko, db + i * 4096);
    }
    asm volatile("s_waitcnt lgkmcnt(0)" ::: "memory");
    __builtin_amdgcn_sched_barrier(0);
    __builtin_amdgcn_s_setprio(1);
#pragma unroll
    for (int i = 0; i < 4; ++i)
#pragma unroll
      for (int j = 0; j < 2; ++j)
#pragma unroll
        for (int kk = 0; kk < 2; ++kk)
          acc[4 + i][j] = __builtin_amdgcn_mfma_f32_16x16x32_bf16(
              afr[i][kk], bf_[j][kk], acc[4 + i][j], 0, 0, 0);
    __builtin_amdgcn_s_setprio(0);
    if (pf) asm volatile("s_waitcnt vmcnt(0)" ::: "memory");
    __builtin_amdgcn_s_barrier();
    s ^= 1;
  }

  const int orow0 = m0 + wr * 128 + g * 4;
#pragma unroll
  for (int m = 0; m < 8; ++m)
#pragma unroll
    for (int n = 0; n < 2; ++n) {
      const int col = bx * 128 + wc * 32 + n * 16 + cl;
#pragma unroll
      for (int r = 0; r < 4; ++r) {
        const size_t idx = (size_t)(orow0 + m * 16 + r) * DMODEL + col;
        X1out[idx] = acc[m][n][r] + resid[idx];
      }
    }
}

// ---------------------------------------------------------------------------
// Combine split-K partials + residual: out = P0 + P1 + X1 (f32, float4)
// ---------------------------------------------------------------------------
__global__ __launch_bounds__(256) void add3_k(const float* __restrict__ P0,
                                              const float* __restrict__ P1,
                                              const float* __restrict__ X1,
                                              float* __restrict__ out) {
  const size_t i = (size_t)blockIdx.x * 256 + threadIdx.x;
  const float4 a = ((const float4*)P0)[i];
  const float4 b = ((const float4*)P1)[i];
  const float4 c = ((const float4*)X1)[i];
  float4 o;
  o.x = a.x + b.x + c.x;
  o.y = a.y + b.y + c.y;
  o.z = a.z + b.z + c.z;
  o.w = a.w + b.w + c.w;
  ((float4*)out)[i] = o;
}

// ---------------------------------------------------------------------------
// RoPE tables: cos/sin [S_LEN][64] f32
// ---------------------------------------------------------------------------
__global__ __launch_bounds__(256) void rope_table_k(float* __restrict__ tc,
                                                    float* __restrict__ ts) {
  const int idx = blockIdx.x * 256 + threadIdx.x;   // S_LEN*64 = 131072
  const int pos = idx >> 6, j = idx & 63;
  const float inv = expf(((float)(2 * j) * (1.0f / 128.0f)) * -logf(10000.0f));
  const float th = (float)pos * inv;
  tc[idx] = cosf(th);
  ts[idx] = sinf(th);
}

// RoPE apply — K ONLY (granule layout); Q rope is fused into attn_k.
__global__ __launch_bounds__(256) void rope_k_only(u16* __restrict__ KG,
                                                   const float* __restrict__ tc,
                                                   const float* __restrict__ ts) {
  const int idx = blockIdx.x * 256 + threadIdx.x;   // 2^22 total
  const int j = idx & 63;
  const int h = (idx >> 6) & (NHEADS - 1);
  const int row = idx >> 10;                        // 0..4095
  const int s = row & (S_LEN - 1);
  const int bh = (row >> 11) * NHEADS + h;
  const float c = tc[s * 64 + j], sn = ts[s * 64 + j];
  u16* p = KG + (size_t)(bh * 32 + (s >> 6)) * 8192 +
           ((j >> 3) * 64 + (s & 63)) * 8 + (j & 7);
  const float x1 = bf2f(p[0]);
  const float x2 = bf2f(p[4096]);
  p[0]    = f2bf(x1 * c - x2 * sn);
  p[4096] = f2bf(x2 * c + x1 * sn);
}

// ---------------------------------------------------------------------------
// Flash attention. 4 waves x 32 q-rows = 128 q/block; KVBLK=64.
// Q rope applied in-register after fragment load.
// ---------------------------------------------------------------------------
__global__ __launch_bounds__(256, 2) void attn_k(const u16* __restrict__ Q,
                                                 const u16* __restrict__ KG,
                                                 const u16* __restrict__ VG,
                                                 u16* __restrict__ O,
                                                 const float* __restrict__ TC,
                                                 const float* __restrict__ TS) {
  __shared__ __align__(16) u16 Ks[2][8192];   // 2 x 16KB (1024 granules: c*64+kv)
  __shared__ __align__(16) u16 Vs[8192];      // 16KB (1024 granules: cs*128+dh)
  __shared__ __align__(16) u16 Ps[4][2048];   // 4KB/wave (256 granules, permuted)
  const int tid = threadIdx.x, lane = tid & 63, wave = tid >> 6;
  const int g = lane >> 4, cl = lane & 15;
  const int qt = blockIdx.x, bh = blockIdx.y;
  const int b = bh >> 4, h = bh & (NHEADS - 1);
  const int qrow0 = b * S_LEN + qt * 128 + wave * 32;   // batch offset included

  // Q fragments: row = qrow0 + qs*16 + cl, d = ks*32 + g*8
  s16x8 aq[2][4];
#pragma unroll
  for (int qs = 0; qs < 2; ++qs)
#pragma unroll
    for (int ks = 0; ks < 4; ++ks)
      aq[qs][ks] = *(const s16x8*)(Q + (size_t)(qrow0 + qs * 16 + cl) * DMODEL +
                                   h * DHEAD + ks * 32 + g * 8);

  // in-register Q RoPE
#pragma unroll
  for (int qs = 0; qs < 2; ++qs) {
    const int s0 = qt * 128 + wave * 32 + qs * 16 + cl;   // seq position
    const float* tcs = TC + s0 * 64 + g * 8;
    const float* tss = TS + s0 * 64 + g * 8;
#pragma unroll
    for (int ks = 0; ks < 2; ++ks)
#pragma unroll
      for (int j = 0; j < 8; ++j) {
        const float c = tcs[ks * 32 + j];
        const float sn = tss[ks * 32 + j];
        const float x1 = bf2f((u16)aq[qs][ks][j]);
        const float x2 = bf2f((u16)aq[qs][ks + 2][j]);
        aq[qs][ks][j]     = (short)f2bf(x1 * c - x2 * sn);
        aq[qs][ks + 2][j] = (short)f2bf(x2 * c + x1 * sn);
      }
  }

  const u16* kgb = KG + (size_t)bh * 32 * 8192;
  const u16* vgb = VG + (size_t)bh * 32 * 8192;

  auto stage_k = [&](int kt, int buf) {
    const u16* sp = kgb + (size_t)kt * 8192 + wave * 2048 + lane * 8;
    u16* dp = &Ks[buf][wave * 2048];
#pragma unroll
    for (int i = 0; i < 4; ++i) gload16(sp + i * 512, dp + i * 512);
  };
  auto stage_v = [&](int kt) {
    const u16* sp = vgb + (size_t)kt * 8192 + wave * 2048 + lane * 8;
    u16* dp = &Vs[wave * 2048];
#pragma unroll
    for (int i = 0; i < 4; ++i) gload16(sp + i * 512, dp + i * 512);
  };

  const float scale = 0.08838834764831845f;  // 1/sqrt(128)
  const f32x4 fz = {0.f, 0.f, 0.f, 0.f};
  f32x4 ctx[2][8];
#pragma unroll
  for (int qs = 0; qs < 2; ++qs)
#pragma unroll
    for (int n = 0; n < 8; ++n) ctx[qs][n] = fz;
  float mx[2][4], lr[2][4];
#pragma unroll
  for (int qs = 0; qs < 2; ++qs)
#pragma unroll
    for (int r = 0; r < 4; ++r) { mx[qs][r] = -1e30f; lr[qs][r] = 0.f; }

  auto body = [&](int it, int buf, bool pref) {
    stage_v(it);
    if (pref) stage_k(it + 1, buf ^ 1);
    f32x4 s[2][4];
#pragma unroll
    for (int qs = 0; qs < 2; ++qs)
#pragma unroll
      for (int t = 0; t < 4; ++t) s[qs][t] = fz;
#pragma unroll
    for (int t = 0; t < 4; ++t) {
      s16x8 kf[4];
#pragma unroll
      for (int ks = 0; ks < 4; ++ks)
        kf[ks] = *(const s16x8*)(&Ks[buf][((ks * 4 + g) * 64 + t * 16 + cl) * 8]);
#pragma unroll
      for (int qs = 0; qs < 2; ++qs)
#pragma unroll
        for (int ks = 0; ks < 4; ++ks)
          s[qs][t] = __builtin_amdgcn_mfma_f32_16x16x32_bf16(aq[qs][ks], kf[ks],
                                                             s[qs][t], 0, 0, 0);
    }
    float corr[2][4];
#pragma unroll
    for (int qs = 0; qs < 2; ++qs)
#pragma unroll
      for (int r = 0; r < 4; ++r) {
        const float a0 = s[qs][0][r] * scale, a1 = s[qs][1][r] * scale;
        const float a2 = s[qs][2][r] * scale, a3 = s[qs][3][r] * scale;
        float v = fmaxf(fmaxf(a0, a1), fmaxf(a2, a3));
        v = red16_max(v);
        const float nm = fmaxf(mx[qs][r], v);
        const float c_ = __expf(mx[qs][r] - nm);
        mx[qs][r] = nm;
        corr[qs][r] = c_;
        const float p0 = __expf(a0 - nm), p1 = __expf(a1 - nm);
        const float p2 = __expf(a2 - nm), p3 = __expf(a3 - nm);
        float rs = (p0 + p1) + (p2 + p3);
        rs = red16_sum(rs);
        lr[qs][r] = lr[qs][r] * c_ + rs;
        const int pb = (qs * 16 + r * 4 + g) * 8 + (cl & 7) + (cl >> 3) * 256;
        Ps[wave][pb]        = f2bf(p0);
        Ps[wave][pb + 512]  = f2bf(p1);
        Ps[wave][pb + 1024] = f2bf(p2);
        Ps[wave][pb + 1536] = f2bf(p3);
      }
#pragma unroll
    for (int qs = 0; qs < 2; ++qs)
#pragma unroll
      for (int n = 0; n < 8; ++n)
#pragma unroll
        for (int r = 0; r < 4; ++r) ctx[qs][n][r] *= corr[qs][r];
    if (pref) asm volatile("s_waitcnt vmcnt(4)" ::: "memory");
    else      asm volatile("s_waitcnt vmcnt(0)" ::: "memory");
    __builtin_amdgcn_s_barrier();
    s16x8 pa[2][2];
#pragma unroll
    for (int qs = 0; qs < 2; ++qs)
#pragma unroll
      for (int k2 = 0; k2 < 2; ++k2)
        pa[qs][k2] = *(const s16x8*)(&Ps[wave][((k2 * 4 + g) * 32 + qs * 16 +
                                                (cl & 3) * 4 + (cl >> 2)) * 8]);
#pragma unroll
    for (int n = 0; n < 8; ++n) {
      s16x8 vf0 = *(const s16x8*)(&Vs[((g) * 128 + n * 16 + cl) * 8]);
      s16x8 vf1 = *(const s16x8*)(&Vs[((4 + g) * 128 + n * 16 + cl) * 8]);
#pragma unroll
      for (int qs = 0; qs < 2; ++qs) {
        ctx[qs][n] = __builtin_amdgcn_mfma_f32_16x16x32_bf16(pa[qs][0], vf0,
                                                             ctx[qs][n], 0, 0, 0);
        ctx[qs][n] = __builtin_amdgcn_mfma_f32_16x16x32_bf16(pa[qs][1], vf1,
                                                             ctx[qs][n], 0, 0, 0);
      }
    }
    asm volatile("s_waitcnt vmcnt(0)" ::: "memory");
    __builtin_amdgcn_s_barrier();
  };

  stage_k(0, 0);
  asm volatile("s_waitcnt vmcnt(0)" ::: "memory");
  __builtin_amdgcn_s_barrier();
#pragma unroll 1
  for (int it = 0; it < 31; ++it) body(it, it & 1, true);
  body(31, 1, false);

#pragma unroll
  for (int qs = 0; qs < 2; ++qs) {
    float inv[4];
#pragma unroll
    for (int r = 0; r < 4; ++r) inv[r] = 1.0f / lr[qs][r];
#pragma unroll
    for (int n = 0; n < 8; ++n)
#pragma unroll
      for (int r = 0; r < 4; ++r)
        O[(size_t)(qrow0 + qs * 16 + g * 4 + r) * DMODEL + h * DHEAD + n * 16 + cl] =
            f2bf(ctx[qs][n][r] * inv[r]);
  }
}

// ---------------------------------------------------------------------------
extern "C" void kernel_launch(void* const* d_in, const int* in_sizes, int n_in,
                              void* d_out, int out_size, void* d_ws, size_t ws_size,
                              hipStream_t stream) {
  (void)in_sizes; (void)n_in; (void)out_size; (void)ws_size;
  const float* x  = (const float*)d_in[0];
  const float* wq = (const float*)d_in[1];
  const float* wk = (const float*)d_in[2];
  const float* wv = (const float*)d_in[3];
  const float* wo = (const float*)d_in[4];
  const float* g1 = (const float*)d_in[5];
  const float* g2 = (const float*)d_in[6];
  const float* w1 = (const float*)d_in[7];
  const float* w2 = (const float*)d_in[8];   // dict order: w1, w2, w3
  const float* w3 = (const float*)d_in[9];
  float* out = (float*)d_out;

  char* ws = (char*)d_ws;
  size_t off = 0;
  auto alloc = [&](size_t bytes) -> char* {
    char* p = ws + off;
    off += (bytes + 255) & ~(size_t)255;
    return p;
  };
  u16* WQT = (u16*)alloc((size_t)DMODEL * DMODEL * 2);   //  8 MB
  u16* WKT = (u16*)alloc((size_t)DMODEL * DMODEL * 2);   //  8 MB
  u16* WVT = (u16*)alloc((size_t)DMODEL * DMODEL * 2);   //  8 MB
  u16* WOT = (u16*)alloc((size_t)DMODEL * DMODEL * 2);   //  8 MB
  u16* QB  = (u16*)alloc((size_t)NROWS * DMODEL * 2);    // 16 MB
  u16* KGb = (u16*)alloc((size_t)NROWS * DMODEL * 2);    // 16 MB (granule layout)
  u16* VGb = (u16*)alloc((size_t)NROWS * DMODEL * 2);    // 16 MB (granule layout)
  u16* W1T = (u16*)alloc((size_t)HID * DMODEL * 2);      // 32 MB
  u16* W3T = (u16*)alloc((size_t)HID * DMODEL * 2);      // 32 MB
  u16* W2T = (u16*)alloc((size_t)DMODEL * HID * 2);      // 32 MB
  u16* Hb  = (u16*)alloc((size_t)NROWS * DMODEL * 2);    // 16 MB (h1 / AO / h2)
  float* X1 = (float*)alloc((size_t)NROWS * DMODEL * 4); // 32 MB
  float* TC = (float*)alloc((size_t)S_LEN * 64 * 4);
  float* TS = (float*)alloc((size_t)S_LEN * 64 * 4);
  // U[4096][8192] bf16 = 64 MB aliases WQT..WOT+QB+KGb (all dead by then)
  u16* U = WQT;
  u16* AO = Hb;   // attention output overwrites h1 (dead after QKV GEMMs)
  // split-K partials: 2 x 32 MB f32, alias W1T+W3T (dead after gemm8_swiglu)
  float* P01 = (float*)W1T;

  const dim3 b256(256);
  const dim3 tb(32, 8);

  rope_table_k<<<dim3(512), b256, 0, stream>>>(TC, TS);
  transpose_cvt<<<dim3(64, 64), tb, 0, stream>>>(wq, WQT, DMODEL, DMODEL);
  transpose_cvt<<<dim3(64, 64), tb, 0, stream>>>(wk, WKT, DMODEL, DMODEL);
  transpose_cvt<<<dim3(64, 64), tb, 0, stream>>>(wv, WVT, DMODEL, DMODEL);
  transpose_cvt<<<dim3(64, 64), tb, 0, stream>>>(wo, WOT, DMODEL, DMODEL);
  transpose_cvt<<<dim3(256, 64), tb, 0, stream>>>(w1, W1T, DMODEL, HID);
  transpose_cvt<<<dim3(256, 64), tb, 0, stream>>>(w3, W3T, DMODEL, HID);
  transpose_cvt<<<dim3(64, 256), tb, 0, stream>>>(w2, W2T, HID, DMODEL);

  rmsnorm_k<<<dim3(NROWS), b256, 0, stream>>>(x, g1, Hb);
  gemm8_qkv<<<dim3(8, 16, 3), dim3(512), 0, stream>>>(Hb, WQT, WKT, WVT,
                                                      QB, KGb, VGb);
  rope_k_only<<<dim3(16384), b256, 0, stream>>>(KGb, TC, TS);
  attn_k<<<dim3(16, 32), b256, 0, stream>>>(QB, KGb, VGb, AO, TC, TS);
  gemm8_wo<<<dim3(16, 16), dim3(512), 0, stream>>>(AO, WOT, x, X1);

  rmsnorm_k<<<dim3(NROWS), b256, 0, stream>>>(X1, g2, Hb);
  gemm8_swiglu<<<dim3(64, 16), dim3(512), 0, stream>>>(Hb, W1T, W3T, U);
  gemm8_down<<<dim3(8, 16, 2), dim3(512), 0, stream>>>(U, W2T, P01);
  add3_k<<<dim3(NROWS * DMODEL / 4 / 256), b256, 0, stream>>>(
      P01, P01 + (size_t)NROWS * DMODEL, X1, out);
}